// Round 1
// baseline (1488.714 us; speedup 1.0000x reference)
//
#include <hip/hip_runtime.h>
#include <math.h>

// ---- problem constants ----
#define B_  8
#define S_  577
#define D_  768
#define H_  12
#define P_  576
#define KW_ 32
#define HD_ 64
constexpr int   MS       = B_ * S_;   // 4616 rows (full seq)
constexpr int   MP       = B_ * P_;   // 4608 rows (patch tokens)
constexpr float SCALE_   = 0.125f;    // HD^-0.5
constexpr float INV_TEMP = 10.0f;     // 1/0.1

// ============================================================
// LayerNorm: one block (256 thr) per row of 768
// ============================================================
__global__ __launch_bounds__(256) void ln_rows(
    const float* __restrict__ X, const float* __restrict__ g,
    const float* __restrict__ bta, float* __restrict__ Y) {
  const int r   = blockIdx.x;
  const int tid = threadIdx.x;
  const float* row = X + (long)r * D_;
  float v[3];
  float s = 0.f, sq = 0.f;
#pragma unroll
  for (int t = 0; t < 3; ++t) {
    v[t] = row[tid + t * 256];
    s += v[t];
    sq = fmaf(v[t], v[t], sq);
  }
#pragma unroll
  for (int off = 32; off; off >>= 1) {
    s  += __shfl_xor(s, off);
    sq += __shfl_xor(sq, off);
  }
  __shared__ float rs[4], rq[4];
  if ((tid & 63) == 0) { rs[tid >> 6] = s; rq[tid >> 6] = sq; }
  __syncthreads();
  s  = rs[0] + rs[1] + rs[2] + rs[3];
  sq = rq[0] + rq[1] + rq[2] + rq[3];
  const float m   = s * (1.f / D_);
  const float var = sq * (1.f / D_) - m * m;
  const float inv = rsqrtf(var + 1e-5f);
#pragma unroll
  for (int t = 0; t < 3; ++t) {
    const int c = tid + t * 256;
    Y[(long)r * D_ + c] = (v[t] - m) * inv * g[c] + bta[c];
  }
}

// ============================================================
// l2-normalize rows of 768 in place
// ============================================================
__global__ __launch_bounds__(256) void l2norm_rows(float* __restrict__ X) {
  const int r   = blockIdx.x;
  const int tid = threadIdx.x;
  float* row = X + (long)r * D_;
  float v[3];
  float sq = 0.f;
#pragma unroll
  for (int t = 0; t < 3; ++t) {
    v[t] = row[tid + t * 256];
    sq = fmaf(v[t], v[t], sq);
  }
#pragma unroll
  for (int off = 32; off; off >>= 1) sq += __shfl_xor(sq, off);
  __shared__ float rq[4];
  if ((tid & 63) == 0) rq[tid >> 6] = sq;
  __syncthreads();
  sq = rq[0] + rq[1] + rq[2] + rq[3];
  const float scale = 1.f / fmaxf(sqrtf(sq), 1e-12f);
#pragma unroll
  for (int t = 0; t < 3; ++t) row[tid + t * 256] = v[t] * scale;
}

// ============================================================
// Generic fp32 GEMM: C[M,N] = A[M,K] @ W[K,N] + bias, tile 128x64x16
// Epilogues: none / exact-GELU / +residual / QKV scatter
// ROWSKIP: A-row r maps to xn row r + r/576 + 1 (skip cls per batch)
// ============================================================
enum { EPI_NONE = 0, EPI_GELU = 1, EPI_ADD = 2, EPI_QKV = 3 };

template <int EPI, bool ROWSKIP>
__global__ __launch_bounds__(256) void gemm_nn(
    const float* __restrict__ A, const float* __restrict__ W,
    const float* __restrict__ bias, const float* __restrict__ R,
    float* __restrict__ C, int M, int N, int K,
    float* __restrict__ Qb, float* __restrict__ Kb, float* __restrict__ Vb) {
  constexpr int BM = 128, BN = 64, BK = 16;
  __shared__ float As[BK][BM + 4];  // k-major, padded (bank + b128 align)
  __shared__ float Bs[BK][BN];
  const int tid = threadIdx.x;
  const int tx = tid & 15, ty = tid >> 4;
  const int bn = blockIdx.x, bm = blockIdx.y;
  const int lar = tid >> 2;          // 0..63  (A row within half-tile)
  const int lak = (tid & 3) << 2;    // 0,4,8,12
  const int lbk = tid >> 4;          // 0..15
  const int lbc = (tid & 15) << 2;   // 0..60
  const int row0 = bm * BM;
  float acc[8][4];
#pragma unroll
  for (int i = 0; i < 8; ++i)
#pragma unroll
    for (int j = 0; j < 4; ++j) acc[i][j] = 0.f;

  for (int k0 = 0; k0 < K; k0 += BK) {
#pragma unroll
    for (int i = 0; i < 2; ++i) {
      const int r = row0 + lar + i * 64;
      float4 v = {0.f, 0.f, 0.f, 0.f};
      if (r < M) {
        const long ar = ROWSKIP ? (long)r + r / P_ + 1 : (long)r;
        v = *(const float4*)(A + ar * (long)K + k0 + lak);
      }
      As[lak + 0][lar + i * 64] = v.x;
      As[lak + 1][lar + i * 64] = v.y;
      As[lak + 2][lar + i * 64] = v.z;
      As[lak + 3][lar + i * 64] = v.w;
    }
    {
      const float4 w = *(const float4*)(W + (long)(k0 + lbk) * N + bn * BN + lbc);
      *(float4*)&Bs[lbk][lbc] = w;
    }
    __syncthreads();
#pragma unroll
    for (int kk = 0; kk < BK; ++kk) {
      float a[8], b[4];
      *(float4*)(a)     = *(const float4*)&As[kk][ty * 8];
      *(float4*)(a + 4) = *(const float4*)&As[kk][ty * 8 + 4];
      *(float4*)(b)     = *(const float4*)&Bs[kk][tx * 4];
#pragma unroll
      for (int i = 0; i < 8; ++i)
#pragma unroll
        for (int j = 0; j < 4; ++j) acc[i][j] = fmaf(a[i], b[j], acc[i][j]);
    }
    __syncthreads();
  }

  const int c0 = bn * BN + tx * 4;
  const float4 bb = *(const float4*)(bias + c0);
#pragma unroll
  for (int i = 0; i < 8; ++i) {
    const int r = row0 + ty * 8 + i;
    if (r >= M) continue;
    float4 v;
    v.x = acc[i][0] + bb.x;
    v.y = acc[i][1] + bb.y;
    v.z = acc[i][2] + bb.z;
    v.w = acc[i][3] + bb.w;
    if (EPI == EPI_GELU) {
      v.x = 0.5f * v.x * (1.f + erff(v.x * 0.70710678118654752f));
      v.y = 0.5f * v.y * (1.f + erff(v.y * 0.70710678118654752f));
      v.z = 0.5f * v.z * (1.f + erff(v.z * 0.70710678118654752f));
      v.w = 0.5f * v.w * (1.f + erff(v.w * 0.70710678118654752f));
    } else if (EPI == EPI_ADD) {
      const float4 rr = *(const float4*)(R + (long)r * N + c0);
      v.x += rr.x; v.y += rr.y; v.z += rr.z; v.w += rr.w;
    }
    if (EPI == EPI_QKV) {
      const int t   = c0 / (H_ * HD_);       // 0,1,2 -> Q,K,V
      const int rem = c0 - t * (H_ * HD_);
      const int h   = rem >> 6;
      const int d   = rem & 63;
      const int b   = r / S_;
      const int ss  = r - b * S_;
      float* dst = (t == 0 ? Qb : (t == 1 ? Kb : Vb)) +
                   (((long)(b * H_ + h) * S_ + ss) << 6) + d;
      *(float4*)dst = v;
    } else {
      *(float4*)(C + (long)r * N + c0) = v;
    }
  }
}

// ============================================================
// scores[b,i,j] = (q[b,i]·k[b,j] + pos[i,j]) * 10 ; diag -> -1e10
// batched NT GEMM, tile 64x64x32
// ============================================================
__global__ __launch_bounds__(256) void scores_nt(
    const float* __restrict__ Qn, const float* __restrict__ Kn,
    const float* __restrict__ pos, float* __restrict__ sc) {
  constexpr int BT = 64, BK = 32;
  __shared__ float Qs[BK][BT + 4];
  __shared__ float Ks[BK][BT + 4];
  const int tid = threadIdx.x;
  const int tx = tid & 15, ty = tid >> 4;
  const int bj = blockIdx.x, bi = blockIdx.y, b = blockIdx.z;
  const float* Qbase = Qn + (long)b * P_ * D_;
  const float* Kbase = Kn + (long)b * P_ * D_;
  const int lr = tid >> 2;         // 0..63
  const int lk = (tid & 3) << 2;   // 0,4,8,12
  float acc[4][4];
#pragma unroll
  for (int i = 0; i < 4; ++i)
#pragma unroll
    for (int j = 0; j < 4; ++j) acc[i][j] = 0.f;

  for (int k0 = 0; k0 < D_; k0 += BK) {
#pragma unroll
    for (int half = 0; half < 2; ++half) {
      const int kk = lk + half * 16;
      const float4 qv =
          *(const float4*)(Qbase + (long)(bi * BT + lr) * D_ + k0 + kk);
      const float4 kv =
          *(const float4*)(Kbase + (long)(bj * BT + lr) * D_ + k0 + kk);
      Qs[kk + 0][lr] = qv.x; Qs[kk + 1][lr] = qv.y;
      Qs[kk + 2][lr] = qv.z; Qs[kk + 3][lr] = qv.w;
      Ks[kk + 0][lr] = kv.x; Ks[kk + 1][lr] = kv.y;
      Ks[kk + 2][lr] = kv.z; Ks[kk + 3][lr] = kv.w;
    }
    __syncthreads();
#pragma unroll
    for (int kk = 0; kk < BK; ++kk) {
      float a[4], bv[4];
      *(float4*)a  = *(const float4*)&Qs[kk][ty * 4];
      *(float4*)bv = *(const float4*)&Ks[kk][tx * 4];
#pragma unroll
      for (int i = 0; i < 4; ++i)
#pragma unroll
        for (int j = 0; j < 4; ++j) acc[i][j] = fmaf(a[i], bv[j], acc[i][j]);
    }
    __syncthreads();
  }
#pragma unroll
  for (int i = 0; i < 4; ++i) {
    const int gi = bi * BT + ty * 4 + i;
#pragma unroll
    for (int j = 0; j < 4; ++j) {
      const int gj = bj * BT + tx * 4 + j;
      float s;
      if (gi == gj) s = -1e9f;
      else          s = acc[i][j] + pos[(long)gi * P_ + gj];
      sc[((long)b * P_ + gi) * P_ + gj] = s * INV_TEMP;
    }
  }
}

// ============================================================
// top-32 of each 576-row + log-softmax weights. One wave per row.
// Tie-break: lower index first (matches jax.lax.top_k).
// ============================================================
__global__ __launch_bounds__(64) void topk_route(
    const float* __restrict__ sc, int* __restrict__ routes,
    float* __restrict__ logw) {
  const int row  = blockIdx.x;  // b*P + p
  const int lane = threadIdx.x;
  const float* srow = sc + (long)row * P_;
  float v[9];
#pragma unroll
  for (int t = 0; t < 9; ++t) v[t] = srow[lane + (t << 6)];
  float selv = 0.f;
  int   selj = 0;
  for (int it = 0; it < KW_; ++it) {
    float bv = -3.0e38f;
    int   bj = 0x7fffffff;
#pragma unroll
    for (int t = 0; t < 9; ++t) {
      if (v[t] > bv) { bv = v[t]; bj = lane + (t << 6); }
    }
#pragma unroll
    for (int off = 32; off; off >>= 1) {
      const float ov = __shfl_xor(bv, off);
      const int   oj = __shfl_xor(bj, off);
      if (ov > bv || (ov == bv && oj < bj)) { bv = ov; bj = oj; }
    }
    if (lane == it) { selv = bv; selj = bj; }
    if ((bj & 63) == lane) v[bj >> 6] = -3.0e38f;  // owner clears
  }
  const float x = (lane < KW_) ? selv : -3.0e38f;
  float m = x;
#pragma unroll
  for (int off = 16; off; off >>= 1) m = fmaxf(m, __shfl_xor(m, off));
  const float e = expf(x - m);
  float s = e;
#pragma unroll
  for (int off = 16; off; off >>= 1) s += __shfl_xor(s, off);
  const float lw = fmaxf(x - m - logf(s), -10.0f);
  if (lane < KW_) {
    routes[(long)row * KW_ + lane] = selj;
    logw[(long)row * KW_ + lane]   = lw;
  }
}

// ============================================================
// gathered patch attention: block = one (b,p); 4 waves cover 12 heads
// ============================================================
__global__ __launch_bounds__(256) void patch_attn(
    const float* __restrict__ Qb, const float* __restrict__ Kb,
    const float* __restrict__ Vb, const int* __restrict__ routes,
    const float* __restrict__ logw, float* __restrict__ attn) {
  const int bp  = blockIdx.x;
  const int b   = bp / P_, p = bp - b * P_;
  const int tid = threadIdx.x;
  const int wv = tid >> 6, lane = tid & 63;
  __shared__ int   rsh[KW_];
  __shared__ float lwsh[KW_];
  if (tid < KW_) {
    rsh[tid]  = routes[(long)bp * KW_ + tid] + 1;  // +1: skip cls row
    lwsh[tid] = logw[(long)bp * KW_ + tid];
  }
  __syncthreads();
  const int s = p + 1;
  for (int h = wv; h < H_; h += 4) {
    const long bhbase = ((long)(b * H_ + h) * S_) << 6;
    const float* qrow = Qb + bhbase + ((long)s << 6);
    float scv = -3.0e38f;
    if (lane < KW_) {
      const float* kr = Kb + bhbase + ((long)rsh[lane] << 6);
      float dot = 0.f;
#pragma unroll
      for (int d = 0; d < HD_; d += 4) {
        const float4 qv = *(const float4*)(qrow + d);
        const float4 kv = *(const float4*)(kr + d);
        dot = fmaf(qv.x, kv.x, dot);
        dot = fmaf(qv.y, kv.y, dot);
        dot = fmaf(qv.z, kv.z, dot);
        dot = fmaf(qv.w, kv.w, dot);
      }
      scv = fmaf(dot, SCALE_, lwsh[lane]);
    }
    float m = scv;
#pragma unroll
    for (int off = 16; off; off >>= 1) m = fmaxf(m, __shfl_xor(m, off));
    const float e = (lane < KW_) ? expf(scv - m) : 0.f;
    float ssum = e;
#pragma unroll
    for (int off = 16; off; off >>= 1) ssum += __shfl_xor(ssum, off);
    const float inv = 1.f / __shfl(ssum, 0);
    const float* Vbase = Vb + bhbase;
    float out = 0.f;
    for (int kw = 0; kw < KW_; ++kw) {
      const float a = __shfl(e, kw);
      out = fmaf(a, Vbase[((long)rsh[kw] << 6) + lane], out);
    }
    attn[((long)b * S_ + s) * D_ + h * HD_ + lane] = out * inv;
  }
}

// ============================================================
// cls-token attention over all S keys: one block per (b,h)
// ============================================================
__global__ __launch_bounds__(256) void cls_attn(
    const float* __restrict__ Qb, const float* __restrict__ Kb,
    const float* __restrict__ Vb, float* __restrict__ attn) {
  const int bh = blockIdx.x;
  const int b = bh / H_, h = bh - b * H_;
  const int tid = threadIdx.x;
  __shared__ float qs[HD_];
  __shared__ float ssh[S_];
  __shared__ float redm[4], reds[4];
  __shared__ float osh[4][HD_];
  const float* Qrow  = Qb + (long)bh * S_ * HD_;  // s = 0
  const float* Kbase = Kb + (long)bh * S_ * HD_;
  const float* Vbase = Vb + (long)bh * S_ * HD_;
  if (tid < HD_) qs[tid] = Qrow[tid];
  __syncthreads();
  float lmax = -3.0e38f;
  for (int j = tid; j < S_; j += 256) {
    const float* kr = Kbase + (long)j * HD_;
    float dot = 0.f;
#pragma unroll
    for (int d = 0; d < HD_; d += 4) {
      const float4 kv = *(const float4*)(kr + d);
      dot = fmaf(kv.x, qs[d + 0], dot);
      dot = fmaf(kv.y, qs[d + 1], dot);
      dot = fmaf(kv.z, qs[d + 2], dot);
      dot = fmaf(kv.w, qs[d + 3], dot);
    }
    dot *= SCALE_;
    ssh[j] = dot;
    lmax = fmaxf(lmax, dot);
  }
#pragma unroll
  for (int off = 32; off; off >>= 1) lmax = fmaxf(lmax, __shfl_xor(lmax, off));
  if ((tid & 63) == 0) redm[tid >> 6] = lmax;
  __syncthreads();
  const float m = fmaxf(fmaxf(redm[0], redm[1]), fmaxf(redm[2], redm[3]));
  float lsum = 0.f;
  for (int j = tid; j < S_; j += 256) {
    const float e = expf(ssh[j] - m);
    ssh[j] = e;
    lsum += e;
  }
#pragma unroll
  for (int off = 32; off; off >>= 1) lsum += __shfl_xor(lsum, off);
  if ((tid & 63) == 0) reds[tid >> 6] = lsum;
  __syncthreads();  // reds visible + all ssh writes visible
  const float inv = 1.f / (reds[0] + reds[1] + reds[2] + reds[3]);
  const int d = tid & 63, qt = tid >> 6;
  float acc = 0.f;
  for (int j = qt; j < S_; j += 4)
    acc = fmaf(ssh[j], Vbase[((long)j << 6) + d], acc);
  osh[qt][d] = acc;
  __syncthreads();
  if (tid < HD_) {
    const float o = (osh[0][tid] + osh[1][tid] + osh[2][tid] + osh[3][tid]) * inv;
    attn[(long)b * S_ * D_ + h * HD_ + tid] = o;  // s = 0
  }
}

// ============================================================
// host-side launch
// ============================================================
extern "C" void kernel_launch(void* const* d_in, const int* in_sizes, int n_in,
                              void* d_out, int out_size, void* d_ws,
                              size_t ws_size, hipStream_t stream) {
  const float* x     = (const float*)d_in[0];
  const float* g1    = (const float*)d_in[1];
  const float* b1    = (const float*)d_in[2];
  const float* wq    = (const float*)d_in[3];
  const float* bq    = (const float*)d_in[4];
  const float* wk    = (const float*)d_in[5];
  const float* bk    = (const float*)d_in[6];
  const float* pos   = (const float*)d_in[7];
  const float* wqkv  = (const float*)d_in[8];
  const float* bqkv  = (const float*)d_in[9];
  const float* wproj = (const float*)d_in[10];
  const float* bproj = (const float*)d_in[11];
  const float* g2    = (const float*)d_in[12];
  const float* b2    = (const float*)d_in[13];
  const float* wm1   = (const float*)d_in[14];
  const float* bm1   = (const float*)d_in[15];
  const float* wm2   = (const float*)d_in[16];
  const float* bm2   = (const float*)d_in[17];
  float* out = (float*)d_out;
  float* ws  = (float*)d_ws;

  constexpr long NSD = (long)MS * D_;  // 3,545,088 (also B*H*S*HD)
  float* xn   = ws;
  float* x1   = xn + NSD;
  float* x1n  = x1 + NSD;
  float* attn = x1n + NSD;
  float* Qb   = attn + NSD;
  float* Kb   = Qb + NSD;
  float* Vb   = Kb + NSD;
  int*   routes = (int*)(Vb + NSD);
  float* logw   = (float*)(routes + (long)MP * KW_);
  float* fre    = logw + (long)MP * KW_;
  // fre region: {qbuf,kbuf,scores} live until top-k, then reused as MLP hidden
  float* qbuf  = fre;
  float* kbuf  = qbuf + (long)MP * D_;
  float* scbuf = kbuf + (long)MP * D_;
  float* hbuf  = fre;

  // 1. LN1
  ln_rows<<<MS, 256, 0, stream>>>(x, g1, b1, xn);
  // 2/3. q,k projections (rows skip cls) ; l2norm
  gemm_nn<EPI_NONE, true><<<dim3(D_ / 64, MP / 128), 256, 0, stream>>>(
      xn, wq, bq, nullptr, qbuf, MP, D_, D_, nullptr, nullptr, nullptr);
  gemm_nn<EPI_NONE, true><<<dim3(D_ / 64, MP / 128), 256, 0, stream>>>(
      xn, wk, bk, nullptr, kbuf, MP, D_, D_, nullptr, nullptr, nullptr);
  l2norm_rows<<<MP, 256, 0, stream>>>(qbuf);
  l2norm_rows<<<MP, 256, 0, stream>>>(kbuf);
  // 4. routing scores (+pos bias, diag mask, /TEMP)
  scores_nt<<<dim3(P_ / 64, P_ / 64, B_), 256, 0, stream>>>(qbuf, kbuf, pos,
                                                            scbuf);
  // 5. top-32 + log-softmax weights
  topk_route<<<MP, 64, 0, stream>>>(scbuf, routes, logw);
  // 6. fused QKV projection, scattered to (B,H,S,HD)
  gemm_nn<EPI_QKV, false><<<dim3((3 * D_) / 64, (MS + 127) / 128), 256, 0,
                            stream>>>(xn, wqkv, bqkv, nullptr, nullptr, MS,
                                      3 * D_, D_, Qb, Kb, Vb);
  // 7. attention
  cls_attn<<<B_ * H_, 256, 0, stream>>>(Qb, Kb, Vb, attn);
  patch_attn<<<MP, 256, 0, stream>>>(Qb, Kb, Vb, routes, logw, attn);
  // 8. output projection + residual
  gemm_nn<EPI_ADD, false><<<dim3(D_ / 64, (MS + 127) / 128), 256, 0, stream>>>(
      attn, wproj, bproj, x, x1, MS, D_, D_, nullptr, nullptr, nullptr);
  // 9. LN2 + MLP
  ln_rows<<<MS, 256, 0, stream>>>(x1, g2, b2, x1n);
  gemm_nn<EPI_GELU, false><<<dim3((4 * D_) / 64, (MS + 127) / 128), 256, 0,
                             stream>>>(x1n, wm1, bm1, nullptr, hbuf, MS, 4 * D_,
                                       D_, nullptr, nullptr, nullptr);
  gemm_nn<EPI_ADD, false><<<dim3(D_ / 64, (MS + 127) / 128), 256, 0, stream>>>(
      hbuf, wm2, bm2, x1, out, MS, D_, 4 * D_, nullptr, nullptr, nullptr);
}

// Round 2
// 797.750 us; speedup vs baseline: 1.8661x; 1.8661x over previous
//
#include <hip/hip_runtime.h>
#include <math.h>

// ---- problem constants ----
#define B_  8
#define S_  577
#define D_  768
#define H_  12
#define P_  576
#define KW_ 32
#define HD_ 64
constexpr int   MS       = B_ * S_;   // 4616 rows (full seq)
constexpr int   MP       = B_ * P_;   // 4608 rows (patch tokens)
constexpr float SCALE_   = 0.125f;    // HD^-0.5
constexpr float INV_TEMP = 10.0f;     // 1/0.1

typedef __attribute__((ext_vector_type(8))) short          bf16x8;
typedef __attribute__((ext_vector_type(4))) float          f32x4;
typedef __attribute__((ext_vector_type(8))) unsigned short us8;

__device__ __forceinline__ unsigned short f2bf(float f) {
  unsigned int x = __float_as_uint(f);
  x += 0x7fffu + ((x >> 16) & 1u);  // round-to-nearest-even
  return (unsigned short)(x >> 16);
}

__device__ __forceinline__ void gl_lds16(const unsigned short* g,
                                         unsigned short* l) {
  __builtin_amdgcn_global_load_lds(
      (const __attribute__((address_space(1))) void*)g,
      (__attribute__((address_space(3))) void*)l, 16, 0, 0);
}

// ============================================================
// LayerNorm: one block (256 thr) per row of 768
// ============================================================
__global__ __launch_bounds__(256) void ln_rows(
    const float* __restrict__ X, const float* __restrict__ g,
    const float* __restrict__ bta, float* __restrict__ Y) {
  const int r   = blockIdx.x;
  const int tid = threadIdx.x;
  const float* row = X + (long)r * D_;
  float v[3];
  float s = 0.f, sq = 0.f;
#pragma unroll
  for (int t = 0; t < 3; ++t) {
    v[t] = row[tid + t * 256];
    s += v[t];
    sq = fmaf(v[t], v[t], sq);
  }
#pragma unroll
  for (int off = 32; off; off >>= 1) {
    s  += __shfl_xor(s, off);
    sq += __shfl_xor(sq, off);
  }
  __shared__ float rs[4], rq[4];
  if ((tid & 63) == 0) { rs[tid >> 6] = s; rq[tid >> 6] = sq; }
  __syncthreads();
  s  = rs[0] + rs[1] + rs[2] + rs[3];
  sq = rq[0] + rq[1] + rq[2] + rq[3];
  const float m   = s * (1.f / D_);
  const float var = sq * (1.f / D_) - m * m;
  const float inv = rsqrtf(var + 1e-5f);
#pragma unroll
  for (int t = 0; t < 3; ++t) {
    const int c = tid + t * 256;
    Y[(long)r * D_ + c] = (v[t] - m) * inv * g[c] + bta[c];
  }
}

// ============================================================
// l2-normalize rows of 768 in place
// ============================================================
__global__ __launch_bounds__(256) void l2norm_rows(float* __restrict__ X) {
  const int r   = blockIdx.x;
  const int tid = threadIdx.x;
  float* row = X + (long)r * D_;
  float v[3];
  float sq = 0.f;
#pragma unroll
  for (int t = 0; t < 3; ++t) {
    v[t] = row[tid + t * 256];
    sq = fmaf(v[t], v[t], sq);
  }
#pragma unroll
  for (int off = 32; off; off >>= 1) sq += __shfl_xor(sq, off);
  __shared__ float rq[4];
  if ((tid & 63) == 0) rq[tid >> 6] = sq;
  __syncthreads();
  sq = rq[0] + rq[1] + rq[2] + rq[3];
  const float scale = 1.f / fmaxf(sqrtf(sq), 1e-12f);
#pragma unroll
  for (int t = 0; t < 3; ++t) row[tid + t * 256] = v[t] * scale;
}

// ============================================================
// fp32 GEMM (routing path only — kept bit-identical to round 1)
// ============================================================
enum { EPI_NONE = 0 };

template <int EPI, bool ROWSKIP>
__global__ __launch_bounds__(256) void gemm_nn(
    const float* __restrict__ A, const float* __restrict__ W,
    const float* __restrict__ bias, const float* __restrict__ R,
    float* __restrict__ C, int M, int N, int K,
    float* __restrict__ Qb, float* __restrict__ Kb, float* __restrict__ Vb) {
  constexpr int BM = 128, BN = 64, BK = 16;
  __shared__ float As[BK][BM + 4];
  __shared__ float Bs[BK][BN];
  const int tid = threadIdx.x;
  const int tx = tid & 15, ty = tid >> 4;
  const int bn = blockIdx.x, bm = blockIdx.y;
  const int lar = tid >> 2;
  const int lak = (tid & 3) << 2;
  const int lbk = tid >> 4;
  const int lbc = (tid & 15) << 2;
  const int row0 = bm * BM;
  float acc[8][4];
#pragma unroll
  for (int i = 0; i < 8; ++i)
#pragma unroll
    for (int j = 0; j < 4; ++j) acc[i][j] = 0.f;

  for (int k0 = 0; k0 < K; k0 += BK) {
#pragma unroll
    for (int i = 0; i < 2; ++i) {
      const int r = row0 + lar + i * 64;
      float4 v = {0.f, 0.f, 0.f, 0.f};
      if (r < M) {
        const long ar = ROWSKIP ? (long)r + r / P_ + 1 : (long)r;
        v = *(const float4*)(A + ar * (long)K + k0 + lak);
      }
      As[lak + 0][lar + i * 64] = v.x;
      As[lak + 1][lar + i * 64] = v.y;
      As[lak + 2][lar + i * 64] = v.z;
      As[lak + 3][lar + i * 64] = v.w;
    }
    {
      const float4 w = *(const float4*)(W + (long)(k0 + lbk) * N + bn * BN + lbc);
      *(float4*)&Bs[lbk][lbc] = w;
    }
    __syncthreads();
#pragma unroll
    for (int kk = 0; kk < BK; ++kk) {
      float a[8], b[4];
      *(float4*)(a)     = *(const float4*)&As[kk][ty * 8];
      *(float4*)(a + 4) = *(const float4*)&As[kk][ty * 8 + 4];
      *(float4*)(b)     = *(const float4*)&Bs[kk][tx * 4];
#pragma unroll
      for (int i = 0; i < 8; ++i)
#pragma unroll
        for (int j = 0; j < 4; ++j) acc[i][j] = fmaf(a[i], b[j], acc[i][j]);
    }
    __syncthreads();
  }

  const int c0 = bn * BN + tx * 4;
  const float4 bb = *(const float4*)(bias + c0);
#pragma unroll
  for (int i = 0; i < 8; ++i) {
    const int r = row0 + ty * 8 + i;
    if (r >= M) continue;
    float4 v;
    v.x = acc[i][0] + bb.x;
    v.y = acc[i][1] + bb.y;
    v.z = acc[i][2] + bb.z;
    v.w = acc[i][3] + bb.w;
    *(float4*)(C + (long)r * N + c0) = v;
  }
}

// ============================================================
// bf16 MFMA GEMM: C[M,N] = A_bf[M,K] @ Wt_bf[N,K]^T (+bias, epi)
// tile 128x128x32, 4 waves (2x2), mfma_f32_16x16x32_bf16
// ============================================================
enum { BEPI_QKV = 0, BEPI_ADD = 1, BEPI_GELU = 2 };

template <int EPI>
__global__ __launch_bounds__(256, 2) void gemm_bf16(
    const unsigned short* __restrict__ A, const unsigned short* __restrict__ Wt,
    const float* __restrict__ bias, const float* __restrict__ R,
    float* __restrict__ C, unsigned short* __restrict__ Cbf,
    int M, int N, int K,
    float* __restrict__ Qb, float* __restrict__ Kb, float* __restrict__ Vb) {
  constexpr int BM = 128, BN = 128, BK = 32;
  __shared__ __align__(16) unsigned short ldsA[BM * BK];
  __shared__ __align__(16) unsigned short ldsB[BN * BK];
  const int tid  = threadIdx.x;
  const int wave = tid >> 6;
  const int lane = tid & 63;
  const int wr = wave >> 1, wc = wave & 1;
  const int l16 = lane & 15, l4 = lane >> 4;
  const int bn = blockIdx.x, bm = blockIdx.y;
  const int row0 = bm * BM;

  f32x4 acc[4][4];
#pragma unroll
  for (int i = 0; i < 4; ++i)
#pragma unroll
    for (int j = 0; j < 4; ++j) acc[i][j] = (f32x4){0.f, 0.f, 0.f, 0.f};

  // staging geometry: chunk c covers (row=c>>2, 8 bf16 at kslot=(c&3)*8)
  const int c0 = tid, c1 = tid + 256;
  int ar0 = row0 + (c0 >> 2); if (ar0 > M - 1) ar0 = M - 1;
  int ar1 = row0 + (c1 >> 2); if (ar1 > M - 1) ar1 = M - 1;
  const int nr0 = bn * BN + (c0 >> 2);
  const int nr1 = bn * BN + (c1 >> 2);
  const unsigned short* ga0 = A + (long)ar0 * K + ((c0 & 3) << 3);
  const unsigned short* ga1 = A + (long)ar1 * K + ((c1 & 3) << 3);
  const unsigned short* gb0 = Wt + (long)nr0 * K + ((c0 & 3) << 3);
  const unsigned short* gb1 = Wt + (long)nr1 * K + ((c1 & 3) << 3);

  for (int k0 = 0; k0 < K; k0 += BK) {
    __syncthreads();
    gl_lds16(ga0 + k0, ldsA + c0 * 8);
    gl_lds16(ga1 + k0, ldsA + c1 * 8);
    gl_lds16(gb0 + k0, ldsB + c0 * 8);
    gl_lds16(gb1 + k0, ldsB + c1 * 8);
    __syncthreads();
    bf16x8 af[4], bfr[4];
#pragma unroll
    for (int i = 0; i < 4; ++i)
      af[i] = *(const bf16x8*)(ldsA + (wr * 64 + i * 16 + l16) * BK + l4 * 8);
#pragma unroll
    for (int j = 0; j < 4; ++j)
      bfr[j] = *(const bf16x8*)(ldsB + (wc * 64 + j * 16 + l16) * BK + l4 * 8);
#pragma unroll
    for (int i = 0; i < 4; ++i)
#pragma unroll
      for (int j = 0; j < 4; ++j)
        acc[i][j] = __builtin_amdgcn_mfma_f32_16x16x32_bf16(af[i], bfr[j],
                                                            acc[i][j], 0, 0, 0);
  }

  // epilogue: D row = (lane>>4)*4 + reg, col = lane&15  [m89-verified]
#pragma unroll
  for (int j = 0; j < 4; ++j) {
    const int gcol = bn * BN + wc * 64 + j * 16 + l16;
    const float bb = bias[gcol];
#pragma unroll
    for (int i = 0; i < 4; ++i) {
      const int grow0 = row0 + wr * 64 + i * 16 + l4 * 4;
#pragma unroll
      for (int r = 0; r < 4; ++r) {
        const int grow = grow0 + r;
        if (grow >= M) continue;
        float v = acc[i][j][r] + bb;
        if (EPI == BEPI_GELU) {
          v = 0.5f * v * (1.f + erff(v * 0.70710678118654752f));
          Cbf[(long)grow * N + gcol] = f2bf(v);
        } else if (EPI == BEPI_ADD) {
          C[(long)grow * N + gcol] = v + R[(long)grow * N + gcol];
        } else {  // BEPI_QKV: scatter to (B,H,S,HD)
          const int t   = gcol / (H_ * HD_);
          const int rem = gcol - t * (H_ * HD_);
          const int h   = rem >> 6;
          const int d   = rem & 63;
          const int b   = grow / S_;
          const int ss  = grow - b * S_;
          float* dst = (t == 0 ? Qb : (t == 1 ? Kb : Vb));
          dst[(((long)(b * H_ + h) * S_ + ss) << 6) + d] = v;
        }
      }
    }
  }
}

// ============================================================
// fp32 [K][N] -> bf16 [N][K] transpose+convert (weights)
// ============================================================
__global__ __launch_bounds__(256) void transpose_bf16(
    const float* __restrict__ W, unsigned short* __restrict__ Wt, int K,
    int N) {
  __shared__ float t[32][33];
  const int tx = threadIdx.x & 31, ty = threadIdx.x >> 5;
  const int n0 = blockIdx.x * 32, k0 = blockIdx.y * 32;
#pragma unroll
  for (int i = ty; i < 32; i += 8)
    t[i][tx] = W[(long)(k0 + i) * N + n0 + tx];
  __syncthreads();
#pragma unroll
  for (int i = ty; i < 32; i += 8)
    Wt[(long)(n0 + i) * K + k0 + tx] = f2bf(t[tx][i]);
}

// fp32 -> bf16 elementwise (activations), n % 8 == 0
__global__ __launch_bounds__(256) void convert_bf16(
    const float* __restrict__ X, unsigned short* __restrict__ Y, long n) {
  const long i = ((long)blockIdx.x * 256 + threadIdx.x) * 8;
  if (i >= n) return;
  const float4 a = *(const float4*)(X + i);
  const float4 b = *(const float4*)(X + i + 4);
  us8 o = {f2bf(a.x), f2bf(a.y), f2bf(a.z), f2bf(a.w),
           f2bf(b.x), f2bf(b.y), f2bf(b.z), f2bf(b.w)};
  *(us8*)(Y + i) = o;
}

// ============================================================
// scores[b,i,j] = (q·k + pos) * 10 ; diag -> -1e10   (fp32, routing)
// ============================================================
__global__ __launch_bounds__(256) void scores_nt(
    const float* __restrict__ Qn, const float* __restrict__ Kn,
    const float* __restrict__ pos, float* __restrict__ sc) {
  constexpr int BT = 64, BK = 32;
  __shared__ float Qs[BK][BT + 4];
  __shared__ float Ks[BK][BT + 4];
  const int tid = threadIdx.x;
  const int tx = tid & 15, ty = tid >> 4;
  const int bj = blockIdx.x, bi = blockIdx.y, b = blockIdx.z;
  const float* Qbase = Qn + (long)b * P_ * D_;
  const float* Kbase = Kn + (long)b * P_ * D_;
  const int lr = tid >> 2;
  const int lk = (tid & 3) << 2;
  float acc[4][4];
#pragma unroll
  for (int i = 0; i < 4; ++i)
#pragma unroll
    for (int j = 0; j < 4; ++j) acc[i][j] = 0.f;

  for (int k0 = 0; k0 < D_; k0 += BK) {
#pragma unroll
    for (int half = 0; half < 2; ++half) {
      const int kk = lk + half * 16;
      const float4 qv =
          *(const float4*)(Qbase + (long)(bi * BT + lr) * D_ + k0 + kk);
      const float4 kv =
          *(const float4*)(Kbase + (long)(bj * BT + lr) * D_ + k0 + kk);
      Qs[kk + 0][lr] = qv.x; Qs[kk + 1][lr] = qv.y;
      Qs[kk + 2][lr] = qv.z; Qs[kk + 3][lr] = qv.w;
      Ks[kk + 0][lr] = kv.x; Ks[kk + 1][lr] = kv.y;
      Ks[kk + 2][lr] = kv.z; Ks[kk + 3][lr] = kv.w;
    }
    __syncthreads();
#pragma unroll
    for (int kk = 0; kk < BK; ++kk) {
      float a[4], bv[4];
      *(float4*)a  = *(const float4*)&Qs[kk][ty * 4];
      *(float4*)bv = *(const float4*)&Ks[kk][tx * 4];
#pragma unroll
      for (int i = 0; i < 4; ++i)
#pragma unroll
        for (int j = 0; j < 4; ++j) acc[i][j] = fmaf(a[i], bv[j], acc[i][j]);
    }
    __syncthreads();
  }
#pragma unroll
  for (int i = 0; i < 4; ++i) {
    const int gi = bi * BT + ty * 4 + i;
#pragma unroll
    for (int j = 0; j < 4; ++j) {
      const int gj = bj * BT + tx * 4 + j;
      float s;
      if (gi == gj) s = -1e9f;
      else          s = acc[i][j] + pos[(long)gi * P_ + gj];
      sc[((long)b * P_ + gi) * P_ + gj] = s * INV_TEMP;
    }
  }
}

// ============================================================
// top-32 of each 576-row + log-softmax weights. One wave per row.
// ============================================================
__global__ __launch_bounds__(64) void topk_route(
    const float* __restrict__ sc, int* __restrict__ routes,
    float* __restrict__ logw) {
  const int row  = blockIdx.x;
  const int lane = threadIdx.x;
  const float* srow = sc + (long)row * P_;
  float v[9];
#pragma unroll
  for (int t = 0; t < 9; ++t) v[t] = srow[lane + (t << 6)];
  float selv = 0.f;
  int   selj = 0;
  for (int it = 0; it < KW_; ++it) {
    float bv = -3.0e38f;
    int   bj = 0x7fffffff;
#pragma unroll
    for (int t = 0; t < 9; ++t) {
      if (v[t] > bv) { bv = v[t]; bj = lane + (t << 6); }
    }
#pragma unroll
    for (int off = 32; off; off >>= 1) {
      const float ov = __shfl_xor(bv, off);
      const int   oj = __shfl_xor(bj, off);
      if (ov > bv || (ov == bv && oj < bj)) { bv = ov; bj = oj; }
    }
    if (lane == it) { selv = bv; selj = bj; }
    if ((bj & 63) == lane) v[bj >> 6] = -3.0e38f;
  }
  const float x = (lane < KW_) ? selv : -3.0e38f;
  float m = x;
#pragma unroll
  for (int off = 16; off; off >>= 1) m = fmaxf(m, __shfl_xor(m, off));
  const float e = expf(x - m);
  float s = e;
#pragma unroll
  for (int off = 16; off; off >>= 1) s += __shfl_xor(s, off);
  const float lw = fmaxf(x - m - logf(s), -10.0f);
  if (lane < KW_) {
    routes[(long)row * KW_ + lane] = selj;
    logw[(long)row * KW_ + lane]   = lw;
  }
}

// ============================================================
// gathered patch attention
// ============================================================
__global__ __launch_bounds__(256) void patch_attn(
    const float* __restrict__ Qb, const float* __restrict__ Kb,
    const float* __restrict__ Vb, const int* __restrict__ routes,
    const float* __restrict__ logw, float* __restrict__ attn) {
  const int bp  = blockIdx.x;
  const int b   = bp / P_, p = bp - b * P_;
  const int tid = threadIdx.x;
  const int wv = tid >> 6, lane = tid & 63;
  __shared__ int   rsh[KW_];
  __shared__ float lwsh[KW_];
  if (tid < KW_) {
    rsh[tid]  = routes[(long)bp * KW_ + tid] + 1;
    lwsh[tid] = logw[(long)bp * KW_ + tid];
  }
  __syncthreads();
  const int s = p + 1;
  for (int h = wv; h < H_; h += 4) {
    const long bhbase = ((long)(b * H_ + h) * S_) << 6;
    const float* qrow = Qb + bhbase + ((long)s << 6);
    float scv = -3.0e38f;
    if (lane < KW_) {
      const float* kr = Kb + bhbase + ((long)rsh[lane] << 6);
      float dot = 0.f;
#pragma unroll
      for (int d = 0; d < HD_; d += 4) {
        const float4 qv = *(const float4*)(qrow + d);
        const float4 kv = *(const float4*)(kr + d);
        dot = fmaf(qv.x, kv.x, dot);
        dot = fmaf(qv.y, kv.y, dot);
        dot = fmaf(qv.z, kv.z, dot);
        dot = fmaf(qv.w, kv.w, dot);
      }
      scv = fmaf(dot, SCALE_, lwsh[lane]);
    }
    float m = scv;
#pragma unroll
    for (int off = 16; off; off >>= 1) m = fmaxf(m, __shfl_xor(m, off));
    const float e = (lane < KW_) ? expf(scv - m) : 0.f;
    float ssum = e;
#pragma unroll
    for (int off = 16; off; off >>= 1) ssum += __shfl_xor(ssum, off);
    const float inv = 1.f / __shfl(ssum, 0);
    const float* Vbase = Vb + bhbase;
    float out = 0.f;
    for (int kw = 0; kw < KW_; ++kw) {
      const float a = __shfl(e, kw);
      out = fmaf(a, Vbase[((long)rsh[kw] << 6) + lane], out);
    }
    attn[((long)b * S_ + s) * D_ + h * HD_ + lane] = out * inv;
  }
}

// ============================================================
// cls-token attention over all S keys
// ============================================================
__global__ __launch_bounds__(256) void cls_attn(
    const float* __restrict__ Qb, const float* __restrict__ Kb,
    const float* __restrict__ Vb, float* __restrict__ attn) {
  const int bh = blockIdx.x;
  const int b = bh / H_, h = bh - b * H_;
  const int tid = threadIdx.x;
  __shared__ float qs[HD_];
  __shared__ float ssh[S_];
  __shared__ float redm[4], reds[4];
  __shared__ float osh[4][HD_];
  const float* Qrow  = Qb + (long)bh * S_ * HD_;
  const float* Kbase = Kb + (long)bh * S_ * HD_;
  const float* Vbase = Vb + (long)bh * S_ * HD_;
  if (tid < HD_) qs[tid] = Qrow[tid];
  __syncthreads();
  float lmax = -3.0e38f;
  for (int j = tid; j < S_; j += 256) {
    const float* kr = Kbase + (long)j * HD_;
    float dot = 0.f;
#pragma unroll
    for (int d = 0; d < HD_; d += 4) {
      const float4 kv = *(const float4*)(kr + d);
      dot = fmaf(kv.x, qs[d + 0], dot);
      dot = fmaf(kv.y, qs[d + 1], dot);
      dot = fmaf(kv.z, qs[d + 2], dot);
      dot = fmaf(kv.w, qs[d + 3], dot);
    }
    dot *= SCALE_;
    ssh[j] = dot;
    lmax = fmaxf(lmax, dot);
  }
#pragma unroll
  for (int off = 32; off; off >>= 1) lmax = fmaxf(lmax, __shfl_xor(lmax, off));
  if ((tid & 63) == 0) redm[tid >> 6] = lmax;
  __syncthreads();
  const float m = fmaxf(fmaxf(redm[0], redm[1]), fmaxf(redm[2], redm[3]));
  float lsum = 0.f;
  for (int j = tid; j < S_; j += 256) {
    const float e = expf(ssh[j] - m);
    ssh[j] = e;
    lsum += e;
  }
#pragma unroll
  for (int off = 32; off; off >>= 1) lsum += __shfl_xor(lsum, off);
  if ((tid & 63) == 0) reds[tid >> 6] = lsum;
  __syncthreads();
  const float inv = 1.f / (reds[0] + reds[1] + reds[2] + reds[3]);
  const int d = tid & 63, qt = tid >> 6;
  float acc = 0.f;
  for (int j = qt; j < S_; j += 4)
    acc = fmaf(ssh[j], Vbase[((long)j << 6) + d], acc);
  osh[qt][d] = acc;
  __syncthreads();
  if (tid < HD_) {
    const float o = (osh[0][tid] + osh[1][tid] + osh[2][tid] + osh[3][tid]) * inv;
    attn[(long)b * S_ * D_ + h * HD_ + tid] = o;
  }
}

// ============================================================
// host-side launch
// ============================================================
extern "C" void kernel_launch(void* const* d_in, const int* in_sizes, int n_in,
                              void* d_out, int out_size, void* d_ws,
                              size_t ws_size, hipStream_t stream) {
  const float* x     = (const float*)d_in[0];
  const float* g1    = (const float*)d_in[1];
  const float* b1    = (const float*)d_in[2];
  const float* wq    = (const float*)d_in[3];
  const float* bq    = (const float*)d_in[4];
  const float* wk    = (const float*)d_in[5];
  const float* bk    = (const float*)d_in[6];
  const float* pos   = (const float*)d_in[7];
  const float* wqkv  = (const float*)d_in[8];
  const float* bqkv  = (const float*)d_in[9];
  const float* wproj = (const float*)d_in[10];
  const float* bproj = (const float*)d_in[11];
  const float* g2    = (const float*)d_in[12];
  const float* b2    = (const float*)d_in[13];
  const float* wm1   = (const float*)d_in[14];
  const float* bm1   = (const float*)d_in[15];
  const float* wm2   = (const float*)d_in[16];
  const float* bm2   = (const float*)d_in[17];
  float* out = (float*)d_out;
  float* ws  = (float*)d_ws;

  constexpr long NSD = (long)MS * D_;        // 3,545,088
  constexpr long MPD = (long)MP * D_;        // 3,538,944
  float* xn   = ws;
  float* x1   = xn + NSD;
  float* x1n  = x1 + NSD;
  float* attn = x1n + NSD;
  float* Qb   = attn + NSD;
  float* Kb   = Qb + NSD;
  float* Vb   = Kb + NSD;
  int*   routes = (int*)(Vb + NSD);
  float* logw   = (float*)(routes + (long)MP * KW_);
  float* fre    = logw + (long)MP * KW_;
  // fre: {qbuf,kbuf,scores} live until top-k, then reused as h_bf (bf16 MLP hidden)
  float* qbuf  = fre;
  float* kbuf  = qbuf + MPD;
  float* scbuf = kbuf + MPD;
  unsigned short* h_bf = (unsigned short*)fre;     // 4616*3072 ushorts
  float* tail = scbuf + (long)B_ * P_ * P_;
  unsigned short* abuf    = (unsigned short*)tail;            // NSD ushorts (shared A-conversion buffer)
  unsigned short* wqkv_t  = abuf + NSD;                       // [2304][768]
  unsigned short* wproj_t = wqkv_t + (long)768 * 2304;        // [768][768]
  unsigned short* wm1_t   = wproj_t + (long)768 * 768;        // [3072][768]
  unsigned short* wm2_t   = wm1_t + (long)768 * 3072;         // [768][3072]

  // weight convert+transpose (bf16, [N][K])
  transpose_bf16<<<dim3(2304 / 32, 768 / 32), 256, 0, stream>>>(wqkv, wqkv_t, 768, 2304);
  transpose_bf16<<<dim3(768 / 32, 768 / 32), 256, 0, stream>>>(wproj, wproj_t, 768, 768);
  transpose_bf16<<<dim3(3072 / 32, 768 / 32), 256, 0, stream>>>(wm1, wm1_t, 768, 3072);
  transpose_bf16<<<dim3(768 / 32, 3072 / 32), 256, 0, stream>>>(wm2, wm2_t, 3072, 768);

  // 1. LN1
  ln_rows<<<MS, 256, 0, stream>>>(x, g1, b1, xn);
  // 2/3. routing path — fp32, bit-identical to round 1
  gemm_nn<EPI_NONE, true><<<dim3(D_ / 64, MP / 128), 256, 0, stream>>>(
      xn, wq, bq, nullptr, qbuf, MP, D_, D_, nullptr, nullptr, nullptr);
  gemm_nn<EPI_NONE, true><<<dim3(D_ / 64, MP / 128), 256, 0, stream>>>(
      xn, wk, bk, nullptr, kbuf, MP, D_, D_, nullptr, nullptr, nullptr);
  l2norm_rows<<<MP, 256, 0, stream>>>(qbuf);
  l2norm_rows<<<MP, 256, 0, stream>>>(kbuf);
  scores_nt<<<dim3(P_ / 64, P_ / 64, B_), 256, 0, stream>>>(qbuf, kbuf, pos, scbuf);
  topk_route<<<MP, 64, 0, stream>>>(scbuf, routes, logw);

  // 6. fused QKV projection (bf16 MFMA), scattered to (B,H,S,HD) fp32
  convert_bf16<<<(int)(NSD / 2048), 256, 0, stream>>>(xn, abuf, NSD);
  gemm_bf16<BEPI_QKV><<<dim3(2304 / 128, (MS + 127) / 128), 256, 0, stream>>>(
      abuf, wqkv_t, bqkv, nullptr, nullptr, nullptr, MS, 2304, D_, Qb, Kb, Vb);

  // 7. attention (fp32)
  cls_attn<<<B_ * H_, 256, 0, stream>>>(Qb, Kb, Vb, attn);
  patch_attn<<<MP, 256, 0, stream>>>(Qb, Kb, Vb, routes, logw, attn);

  // 8. output projection + residual (bf16 MFMA)
  convert_bf16<<<(int)(NSD / 2048), 256, 0, stream>>>(attn, abuf, NSD);
  gemm_bf16<BEPI_ADD><<<dim3(D_ / 128, (MS + 127) / 128), 256, 0, stream>>>(
      abuf, wproj_t, bproj, x, x1, nullptr, MS, D_, D_, nullptr, nullptr, nullptr);

  // 9. LN2 + MLP (bf16 MFMA; MLP1 writes bf16 hidden directly)
  ln_rows<<<MS, 256, 0, stream>>>(x1, g2, b2, x1n);
  convert_bf16<<<(int)(NSD / 2048), 256, 0, stream>>>(x1n, abuf, NSD);
  gemm_bf16<BEPI_GELU><<<dim3(3072 / 128, (MS + 127) / 128), 256, 0, stream>>>(
      abuf, wm1_t, bm1, nullptr, nullptr, h_bf, MS, 3072, D_, nullptr, nullptr, nullptr);
  gemm_bf16<BEPI_ADD><<<dim3(D_ / 128, (MS + 127) / 128), 256, 0, stream>>>(
      h_bf, wm2_t, bm2, x1, out, nullptr, MS, D_, 3072, nullptr, nullptr, nullptr);
}

// Round 4
// 693.274 us; speedup vs baseline: 2.1474x; 1.1507x over previous
//
#include <hip/hip_runtime.h>
#include <math.h>

// ---- problem constants ----
#define B_  8
#define S_  577
#define D_  768
#define H_  12
#define P_  576
#define KW_ 32
#define HD_ 64
constexpr int   MS       = B_ * S_;   // 4616
constexpr int   MP       = B_ * P_;   // 4608
constexpr float SCALE_   = 0.125f;
constexpr float INV_TEMP = 10.0f;

typedef __attribute__((ext_vector_type(8))) short bf16x8;
typedef __attribute__((ext_vector_type(4))) float f32x4;

__device__ __forceinline__ unsigned short f2bf(float f) {
  unsigned int x = __float_as_uint(f);
  x += 0x7fffu + ((x >> 16) & 1u);  // RNE
  return (unsigned short)(x >> 16);
}
__device__ __forceinline__ float bf2f(unsigned short h) {
  return __uint_as_float((unsigned int)h << 16);
}
__device__ __forceinline__ void gl_lds16(const unsigned short* g,
                                         unsigned short* l) {
  __builtin_amdgcn_global_load_lds(
      (const __attribute__((address_space(1))) void*)g,
      (__attribute__((address_space(3))) void*)l, 16, 0, 0);
}

// ============================================================
// LayerNorm -> bf16 hi (+ optional lo). One block per row.
// ============================================================
template <bool LO>
__global__ __launch_bounds__(256) void ln_rows_bf(
    const float* __restrict__ X, const float* __restrict__ g,
    const float* __restrict__ bta, unsigned short* __restrict__ Yh,
    unsigned short* __restrict__ Yl) {
  const int r = blockIdx.x, tid = threadIdx.x;
  const float* row = X + (long)r * D_;
  float v[3];
  float s = 0.f, sq = 0.f;
#pragma unroll
  for (int t = 0; t < 3; ++t) {
    v[t] = row[tid + t * 256];
    s += v[t];
    sq = fmaf(v[t], v[t], sq);
  }
#pragma unroll
  for (int off = 32; off; off >>= 1) {
    s  += __shfl_xor(s, off);
    sq += __shfl_xor(sq, off);
  }
  __shared__ float rs[4], rq[4];
  if ((tid & 63) == 0) { rs[tid >> 6] = s; rq[tid >> 6] = sq; }
  __syncthreads();
  s  = rs[0] + rs[1] + rs[2] + rs[3];
  sq = rq[0] + rq[1] + rq[2] + rq[3];
  const float m   = s * (1.f / D_);
  const float var = sq * (1.f / D_) - m * m;
  const float inv = rsqrtf(var + 1e-5f);
#pragma unroll
  for (int t = 0; t < 3; ++t) {
    const int c = tid + t * 256;
    const float y = (v[t] - m) * inv * g[c] + bta[c];
    const unsigned short h = f2bf(y);
    Yh[(long)r * D_ + c] = h;
    if (LO) Yl[(long)r * D_ + c] = f2bf(y - bf2f(h));
  }
}

// ============================================================
// l2-normalize fp32 row -> bf16 hi/lo
// ============================================================
__global__ __launch_bounds__(256) void l2norm_hl(
    const float* __restrict__ X, unsigned short* __restrict__ Yh,
    unsigned short* __restrict__ Yl) {
  const int r = blockIdx.x, tid = threadIdx.x;
  const float* row = X + (long)r * D_;
  float v[3];
  float sq = 0.f;
#pragma unroll
  for (int t = 0; t < 3; ++t) {
    v[t] = row[tid + t * 256];
    sq = fmaf(v[t], v[t], sq);
  }
#pragma unroll
  for (int off = 32; off; off >>= 1) sq += __shfl_xor(sq, off);
  __shared__ float rq[4];
  if ((tid & 63) == 0) rq[tid >> 6] = sq;
  __syncthreads();
  sq = rq[0] + rq[1] + rq[2] + rq[3];
  const float sc = 1.f / fmaxf(sqrtf(sq), 1e-12f);
#pragma unroll
  for (int t = 0; t < 3; ++t) {
    const float y = v[t] * sc;
    const unsigned short h = f2bf(y);
    Yh[(long)r * D_ + tid + t * 256] = h;
    Yl[(long)r * D_ + tid + t * 256] = f2bf(y - bf2f(h));
  }
}

// ============================================================
// weight transpose fp32[K][N] -> bf16 [rowoff+N][K] hi (+lo)
// ============================================================
__global__ __launch_bounds__(256) void transpose_hl(
    const float* __restrict__ W, unsigned short* __restrict__ Th,
    unsigned short* __restrict__ Tl, int K, int N, int rowoff) {
  __shared__ float t[32][33];
  const int tx = threadIdx.x & 31, ty = threadIdx.x >> 5;
  const int n0 = blockIdx.x * 32, k0 = blockIdx.y * 32;
#pragma unroll
  for (int i = ty; i < 32; i += 8)
    t[i][tx] = W[(long)(k0 + i) * N + n0 + tx];
  __syncthreads();
#pragma unroll
  for (int i = ty; i < 32; i += 8) {
    const float w = t[tx][i];
    const unsigned short h = f2bf(w);
    const long o = (long)(rowoff + n0 + i) * K + k0 + tx;
    Th[o] = h;
    if (Tl) Tl[o] = f2bf(w - bf2f(h));
  }
}

// ============================================================
// bf16 MFMA GEMM (smooth path): C = A @ Wt^T + bias, 128x128x32
// ============================================================
enum { BEPI_QKV = 0, BEPI_ADD = 1, BEPI_GELU = 2 };

template <int EPI>
__global__ __launch_bounds__(256, 2) void gemm_bf16(
    const unsigned short* __restrict__ A, const unsigned short* __restrict__ Wt,
    const float* __restrict__ bias, const float* __restrict__ R,
    float* __restrict__ C, unsigned short* __restrict__ Cbf,
    int M, int N, int K,
    float* __restrict__ Qb, float* __restrict__ Kb, float* __restrict__ Vb) {
  constexpr int BK = 32;
  __shared__ __align__(16) unsigned short ldsA[128 * BK];
  __shared__ __align__(16) unsigned short ldsB[128 * BK];
  const int tid = threadIdx.x, wave = tid >> 6, lane = tid & 63;
  const int wr = wave >> 1, wc = wave & 1;
  const int l16 = lane & 15, l4 = lane >> 4;
  const int bn = blockIdx.x, bm = blockIdx.y;
  const int row0 = bm * 128;

  f32x4 acc[4][4];
#pragma unroll
  for (int i = 0; i < 4; ++i)
#pragma unroll
    for (int j = 0; j < 4; ++j) acc[i][j] = (f32x4){0.f, 0.f, 0.f, 0.f};

  const int c0 = tid, c1 = tid + 256;
  int ar0 = row0 + (c0 >> 2); if (ar0 > M - 1) ar0 = M - 1;
  int ar1 = row0 + (c1 >> 2); if (ar1 > M - 1) ar1 = M - 1;
  const unsigned short* ga0 = A + (long)ar0 * K + ((c0 & 3) << 3);
  const unsigned short* ga1 = A + (long)ar1 * K + ((c1 & 3) << 3);
  const unsigned short* gb0 = Wt + (long)(bn * 128 + (c0 >> 2)) * K + ((c0 & 3) << 3);
  const unsigned short* gb1 = Wt + (long)(bn * 128 + (c1 >> 2)) * K + ((c1 & 3) << 3);

  for (int k0 = 0; k0 < K; k0 += BK) {
    __syncthreads();
    gl_lds16(ga0 + k0, ldsA + c0 * 8);
    gl_lds16(ga1 + k0, ldsA + c1 * 8);
    gl_lds16(gb0 + k0, ldsB + c0 * 8);
    gl_lds16(gb1 + k0, ldsB + c1 * 8);
    __syncthreads();
    bf16x8 af[4], bfr[4];
#pragma unroll
    for (int i = 0; i < 4; ++i)
      af[i] = *(const bf16x8*)(ldsA + (wr * 64 + i * 16 + l16) * BK + l4 * 8);
#pragma unroll
    for (int j = 0; j < 4; ++j)
      bfr[j] = *(const bf16x8*)(ldsB + (wc * 64 + j * 16 + l16) * BK + l4 * 8);
#pragma unroll
    for (int i = 0; i < 4; ++i)
#pragma unroll
      for (int j = 0; j < 4; ++j)
        acc[i][j] = __builtin_amdgcn_mfma_f32_16x16x32_bf16(af[i], bfr[j],
                                                            acc[i][j], 0, 0, 0);
  }

#pragma unroll
  for (int j = 0; j < 4; ++j) {
    const int gcol = bn * 128 + wc * 64 + j * 16 + l16;
    const float bb = bias[gcol];
#pragma unroll
    for (int i = 0; i < 4; ++i) {
      const int grow0 = row0 + wr * 64 + i * 16 + l4 * 4;
#pragma unroll
      for (int r = 0; r < 4; ++r) {
        const int grow = grow0 + r;
        if (grow >= M) continue;
        float v = acc[i][j][r] + bb;
        if (EPI == BEPI_GELU) {
          v = 0.5f * v * (1.f + erff(v * 0.70710678118654752f));
          Cbf[(long)grow * N + gcol] = f2bf(v);
        } else if (EPI == BEPI_ADD) {
          C[(long)grow * N + gcol] = v + R[(long)grow * N + gcol];
        } else {  // BEPI_QKV
          const int t   = gcol / (H_ * HD_);
          const int rem = gcol - t * (H_ * HD_);
          const int h   = rem >> 6;
          const int d   = rem & 63;
          const int b   = grow / S_;
          const int ss  = grow - b * S_;
          float* dst = (t == 0 ? Qb : (t == 1 ? Kb : Vb));
          dst[(((long)(b * H_ + h) * S_ + ss) << 6) + d] = v;
        }
      }
    }
  }
}

// ============================================================
// routing projection: bf16x3 emulated-fp32 GEMM
// C[4608][1536] = xn_patch @ [wq|wk] ; phases hi*hi + hi*lo + lo*hi
// ============================================================
__global__ __launch_bounds__(256, 2) void gemm_rproj(
    const unsigned short* __restrict__ Ahi, const unsigned short* __restrict__ Alo,
    const unsigned short* __restrict__ Whi, const unsigned short* __restrict__ Wlo,
    const float* __restrict__ bq, const float* __restrict__ bk,
    float* __restrict__ qout, float* __restrict__ kout) {
  constexpr int BK = 32, K = D_;
  __shared__ __align__(16) unsigned short ldsA[128 * BK];
  __shared__ __align__(16) unsigned short ldsB[128 * BK];
  const int tid = threadIdx.x, wave = tid >> 6, lane = tid & 63;
  const int wr = wave >> 1, wc = wave & 1;
  const int l16 = lane & 15, l4 = lane >> 4;
  const int bn = blockIdx.x, bm = blockIdx.y;
  const int row0 = bm * 128;

  f32x4 acc[4][4];
#pragma unroll
  for (int i = 0; i < 4; ++i)
#pragma unroll
    for (int j = 0; j < 4; ++j) acc[i][j] = (f32x4){0.f, 0.f, 0.f, 0.f};

  const int c0 = tid, c1 = tid + 256;
  const int r0 = row0 + (c0 >> 2), r1 = row0 + (c1 >> 2);
  const long aoff0 = (long)(r0 + r0 / P_ + 1) * K + ((c0 & 3) << 3);
  const long aoff1 = (long)(r1 + r1 / P_ + 1) * K + ((c1 & 3) << 3);
  const long boff0 = (long)(bn * 128 + (c0 >> 2)) * K + ((c0 & 3) << 3);
  const long boff1 = (long)(bn * 128 + (c1 >> 2)) * K + ((c1 & 3) << 3);

  for (int ph = 0; ph < 3; ++ph) {
    const unsigned short* As = (ph < 2) ? Ahi : Alo;
    const unsigned short* Bs = (ph == 1) ? Wlo : Whi;
    for (int k0 = 0; k0 < K; k0 += BK) {
      __syncthreads();
      gl_lds16(As + aoff0 + k0, ldsA + c0 * 8);
      gl_lds16(As + aoff1 + k0, ldsA + c1 * 8);
      gl_lds16(Bs + boff0 + k0, ldsB + c0 * 8);
      gl_lds16(Bs + boff1 + k0, ldsB + c1 * 8);
      __syncthreads();
      bf16x8 af[4], bfr[4];
#pragma unroll
      for (int i = 0; i < 4; ++i)
        af[i] = *(const bf16x8*)(ldsA + (wr * 64 + i * 16 + l16) * BK + l4 * 8);
#pragma unroll
      for (int j = 0; j < 4; ++j)
        bfr[j] = *(const bf16x8*)(ldsB + (wc * 64 + j * 16 + l16) * BK + l4 * 8);
#pragma unroll
      for (int i = 0; i < 4; ++i)
#pragma unroll
        for (int j = 0; j < 4; ++j)
          acc[i][j] = __builtin_amdgcn_mfma_f32_16x16x32_bf16(af[i], bfr[j],
                                                              acc[i][j], 0, 0, 0);
    }
  }

#pragma unroll
  for (int j = 0; j < 4; ++j) {
    const int gcol = bn * 128 + wc * 64 + j * 16 + l16;
    const float bb = (gcol < D_) ? bq[gcol] : bk[gcol - D_];
#pragma unroll
    for (int i = 0; i < 4; ++i) {
      const int grow0 = row0 + wr * 64 + i * 16 + l4 * 4;
#pragma unroll
      for (int r = 0; r < 4; ++r) {
        const int grow = grow0 + r;
        const float v = acc[i][j][r] + bb;
        if (gcol < D_) qout[(long)grow * D_ + gcol] = v;
        else           kout[(long)grow * D_ + gcol - D_] = v;
      }
    }
  }
}

// ============================================================
// routing scores: batched bf16x3 NT GEMM + pos bias + diag + x10
// ============================================================
__global__ __launch_bounds__(256, 2) void gemm_scores(
    const unsigned short* __restrict__ Qh, const unsigned short* __restrict__ Ql,
    const unsigned short* __restrict__ Kh, const unsigned short* __restrict__ Kl,
    const float* __restrict__ pos, float* __restrict__ sc) {
  constexpr int BK = 32, K = D_;
  __shared__ __align__(16) unsigned short ldsA[128 * BK];
  __shared__ __align__(16) unsigned short ldsB[128 * BK];
  const int tid = threadIdx.x, wave = tid >> 6, lane = tid & 63;
  const int wr = wave >> 1, wc = wave & 1;
  const int l16 = lane & 15, l4 = lane >> 4;
  const int bn = blockIdx.x, bm = blockIdx.y, b = blockIdx.z;
  const long base = (long)b * P_ * K;
  const int row0 = bm * 128;

  f32x4 acc[4][4];
#pragma unroll
  for (int i = 0; i < 4; ++i)
#pragma unroll
    for (int j = 0; j < 4; ++j) acc[i][j] = (f32x4){0.f, 0.f, 0.f, 0.f};

  const int c0 = tid, c1 = tid + 256;
  int r0 = row0 + (c0 >> 2); if (r0 > P_ - 1) r0 = P_ - 1;
  int r1 = row0 + (c1 >> 2); if (r1 > P_ - 1) r1 = P_ - 1;
  int n0 = bn * 128 + (c0 >> 2); if (n0 > P_ - 1) n0 = P_ - 1;
  int n1 = bn * 128 + (c1 >> 2); if (n1 > P_ - 1) n1 = P_ - 1;
  const long aoff0 = base + (long)r0 * K + ((c0 & 3) << 3);
  const long aoff1 = base + (long)r1 * K + ((c1 & 3) << 3);
  const long boff0 = base + (long)n0 * K + ((c0 & 3) << 3);
  const long boff1 = base + (long)n1 * K + ((c1 & 3) << 3);

  for (int ph = 0; ph < 3; ++ph) {
    const unsigned short* As = (ph < 2) ? Qh : Ql;
    const unsigned short* Bs = (ph == 1) ? Kl : Kh;
    for (int k0 = 0; k0 < K; k0 += BK) {
      __syncthreads();
      gl_lds16(As + aoff0 + k0, ldsA + c0 * 8);
      gl_lds16(As + aoff1 + k0, ldsA + c1 * 8);
      gl_lds16(Bs + boff0 + k0, ldsB + c0 * 8);
      gl_lds16(Bs + boff1 + k0, ldsB + c1 * 8);
      __syncthreads();
      bf16x8 af[4], bfr[4];
#pragma unroll
      for (int i = 0; i < 4; ++i)
        af[i] = *(const bf16x8*)(ldsA + (wr * 64 + i * 16 + l16) * BK + l4 * 8);
#pragma unroll
      for (int j = 0; j < 4; ++j)
        bfr[j] = *(const bf16x8*)(ldsB + (wc * 64 + j * 16 + l16) * BK + l4 * 8);
#pragma unroll
      for (int i = 0; i < 4; ++i)
#pragma unroll
        for (int j = 0; j < 4; ++j)
          acc[i][j] = __builtin_amdgcn_mfma_f32_16x16x32_bf16(af[i], bfr[j],
                                                              acc[i][j], 0, 0, 0);
    }
  }

#pragma unroll
  for (int j = 0; j < 4; ++j) {
    const int gj = bn * 128 + wc * 64 + j * 16 + l16;
    if (gj >= P_) continue;
#pragma unroll
    for (int i = 0; i < 4; ++i) {
      const int grow0 = row0 + wr * 64 + i * 16 + l4 * 4;
#pragma unroll
      for (int r = 0; r < 4; ++r) {
        const int gi = grow0 + r;
        if (gi >= P_) continue;
        const float s = (gi == gj) ? -1e9f : acc[i][j][r] + pos[(long)gi * P_ + gj];
        sc[((long)b * P_ + gi) * P_ + gj] = s * INV_TEMP;
      }
    }
  }
}

// ============================================================
// top-32 + log-softmax weights. One wave per row.
// ============================================================
__global__ __launch_bounds__(64) void topk_route(
    const float* __restrict__ sc, int* __restrict__ routes,
    float* __restrict__ logw) {
  const int row = blockIdx.x, lane = threadIdx.x;
  const float* srow = sc + (long)row * P_;
  float v[9];
#pragma unroll
  for (int t = 0; t < 9; ++t) v[t] = srow[lane + (t << 6)];
  float selv = 0.f;
  int   selj = 0;
  for (int it = 0; it < KW_; ++it) {
    float bv = -3.0e38f;
    int   bj = 0x7fffffff;
#pragma unroll
    for (int t = 0; t < 9; ++t) {
      if (v[t] > bv) { bv = v[t]; bj = lane + (t << 6); }
    }
#pragma unroll
    for (int off = 32; off; off >>= 1) {
      const float ov = __shfl_xor(bv, off);
      const int   oj = __shfl_xor(bj, off);
      if (ov > bv || (ov == bv && oj < bj)) { bv = ov; bj = oj; }
    }
    if (lane == it) { selv = bv; selj = bj; }
    if ((bj & 63) == lane) v[bj >> 6] = -3.0e38f;
  }
  const float x = (lane < KW_) ? selv : -3.0e38f;
  float m = x;
#pragma unroll
  for (int off = 16; off; off >>= 1) m = fmaxf(m, __shfl_xor(m, off));
  const float e = expf(x - m);
  float s = e;
#pragma unroll
  for (int off = 16; off; off >>= 1) s += __shfl_xor(s, off);
  const float lw = fmaxf(x - m - logf(s), -10.0f);
  if (lane < KW_) {
    routes[(long)row * KW_ + lane] = selj;
    logw[(long)row * KW_ + lane]   = lw;
  }
}

// ============================================================
// gathered patch attention (batch->XCD swizzled, bf16 out)
// grid: 4608 blocks, blockIdx.x = p*8 + b
// ============================================================
__global__ __launch_bounds__(256) void patch_attn(
    const float* __restrict__ Qb, const float* __restrict__ Kb,
    const float* __restrict__ Vb, const int* __restrict__ routes,
    const float* __restrict__ logw, unsigned short* __restrict__ attn) {
  const int b = blockIdx.x & 7, p = blockIdx.x >> 3;
  const int bp = b * P_ + p;
  const int tid = threadIdx.x;
  const int wv = tid >> 6, lane = tid & 63;
  __shared__ int   rsh[KW_];
  __shared__ float lwsh[KW_];
  if (tid < KW_) {
    rsh[tid]  = routes[(long)bp * KW_ + tid] + 1;
    lwsh[tid] = logw[(long)bp * KW_ + tid];
  }
  __syncthreads();
  const int s = p + 1;
  const int kk = lane & 31, half = lane >> 5;
  for (int h = wv; h < H_; h += 4) {
    const long bhbase = ((long)(b * H_ + h) * S_) << 6;
    const float* qh = Qb + bhbase + ((long)s << 6) + (half << 5);
    const float* kr = Kb + bhbase + ((long)rsh[kk] << 6) + (half << 5);
    float dot = 0.f;
#pragma unroll
    for (int d = 0; d < 32; d += 4) {
      const float4 qv = *(const float4*)(qh + d);
      const float4 kv = *(const float4*)(kr + d);
      dot = fmaf(qv.x, kv.x, dot);
      dot = fmaf(qv.y, kv.y, dot);
      dot = fmaf(qv.z, kv.z, dot);
      dot = fmaf(qv.w, kv.w, dot);
    }
    dot += __shfl_xor(dot, 32);
    const float scv = fmaf(dot, SCALE_, lwsh[kk]);
    float m = scv;
#pragma unroll
    for (int off = 16; off; off >>= 1) m = fmaxf(m, __shfl_xor(m, off));
    const float e = expf(scv - m);
    float ssum = e;
#pragma unroll
    for (int off = 16; off; off >>= 1) ssum += __shfl_xor(ssum, off);
    const float inv = 1.f / ssum;
    const float* Vbase = Vb + bhbase;
    float out = 0.f;
    for (int kw = 0; kw < KW_; ++kw) {
      const float a = __shfl(e, kw);
      out = fmaf(a, Vbase[((long)rsh[kw] << 6) + lane], out);
    }
    attn[((long)b * S_ + s) * D_ + h * HD_ + lane] = f2bf(out * inv);
  }
}

// ============================================================
// cls-token attention (bf16 out)
// ============================================================
__global__ __launch_bounds__(256) void cls_attn(
    const float* __restrict__ Qb, const float* __restrict__ Kb,
    const float* __restrict__ Vb, unsigned short* __restrict__ attn) {
  const int bh = blockIdx.x;
  const int b = bh / H_, h = bh - b * H_;
  const int tid = threadIdx.x;
  __shared__ float qs[HD_];
  __shared__ float ssh[S_];
  __shared__ float redm[4], reds[4];
  __shared__ float osh[4][HD_];
  const float* Qrow  = Qb + (long)bh * S_ * HD_;
  const float* Kbase = Kb + (long)bh * S_ * HD_;
  const float* Vbase = Vb + (long)bh * S_ * HD_;
  if (tid < HD_) qs[tid] = Qrow[tid];
  __syncthreads();
  float lmax = -3.0e38f;
  for (int j = tid; j < S_; j += 256) {
    const float* kr = Kbase + (long)j * HD_;
    float dot = 0.f;
#pragma unroll
    for (int d = 0; d < HD_; d += 4) {
      const float4 kv = *(const float4*)(kr + d);
      dot = fmaf(kv.x, qs[d + 0], dot);
      dot = fmaf(kv.y, qs[d + 1], dot);
      dot = fmaf(kv.z, qs[d + 2], dot);
      dot = fmaf(kv.w, qs[d + 3], dot);
    }
    dot *= SCALE_;
    ssh[j] = dot;
    lmax = fmaxf(lmax, dot);
  }
#pragma unroll
  for (int off = 32; off; off >>= 1) lmax = fmaxf(lmax, __shfl_xor(lmax, off));
  if ((tid & 63) == 0) redm[tid >> 6] = lmax;
  __syncthreads();
  const float m = fmaxf(fmaxf(redm[0], redm[1]), fmaxf(redm[2], redm[3]));
  float lsum = 0.f;
  for (int j = tid; j < S_; j += 256) {
    const float e = expf(ssh[j] - m);
    ssh[j] = e;
    lsum += e;
  }
#pragma unroll
  for (int off = 32; off; off >>= 1) lsum += __shfl_xor(lsum, off);
  if ((tid & 63) == 0) reds[tid >> 6] = lsum;
  __syncthreads();
  const float inv = 1.f / (reds[0] + reds[1] + reds[2] + reds[3]);
  const int d = tid & 63, qt = tid >> 6;
  float acc = 0.f;
  for (int j = qt; j < S_; j += 4)
    acc = fmaf(ssh[j], Vbase[((long)j << 6) + d], acc);
  osh[qt][d] = acc;
  __syncthreads();
  if (tid < HD_) {
    const float o = (osh[0][tid] + osh[1][tid] + osh[2][tid] + osh[3][tid]) * inv;
    attn[(long)b * S_ * D_ + h * HD_ + tid] = f2bf(o);
  }
}

// ============================================================
// host-side launch
// ============================================================
extern "C" void kernel_launch(void* const* d_in, const int* in_sizes, int n_in,
                              void* d_out, int out_size, void* d_ws,
                              size_t ws_size, hipStream_t stream) {
  const float* x     = (const float*)d_in[0];
  const float* g1    = (const float*)d_in[1];
  const float* b1    = (const float*)d_in[2];
  const float* wq    = (const float*)d_in[3];
  const float* bq    = (const float*)d_in[4];
  const float* wk    = (const float*)d_in[5];
  const float* bk    = (const float*)d_in[6];
  const float* pos   = (const float*)d_in[7];
  const float* wqkv  = (const float*)d_in[8];
  const float* bqkv  = (const float*)d_in[9];
  const float* wproj = (const float*)d_in[10];
  const float* bproj = (const float*)d_in[11];
  const float* g2    = (const float*)d_in[12];
  const float* b2    = (const float*)d_in[13];
  const float* wm1   = (const float*)d_in[14];
  const float* bm1   = (const float*)d_in[15];
  const float* wm2   = (const float*)d_in[16];
  const float* bm2   = (const float*)d_in[17];
  float* out = (float*)d_out;

  constexpr long NSD = (long)MS * D_;   // 3,545,088
  constexpr long MPD = (long)MP * D_;   // 3,538,944
  constexpr long SCL = (long)B_ * P_ * P_;  // 2,654,208

  unsigned short* xn_hi = (unsigned short*)d_ws;
  unsigned short* xn_lo = xn_hi + NSD;
  float* x1 = (float*)(xn_lo + NSD);
  float* Qb = x1 + NSD;
  float* Kb = Qb + NSD;
  float* Vb = Kb + NSD;
  int*   routes = (int*)(Vb + NSD);
  float* logw   = (float*)(routes + (long)MP * KW_);
  // region R1: qbuf+kbuf (fp32, transient) -> later h_bf (bf16 MLP hidden)
  float* R1   = logw + (long)MP * KW_;
  float* qbuf = R1;
  float* kbuf = qbuf + MPD;
  unsigned short* h_bf = (unsigned short*)R1;      // 4616*3072 shorts
  constexpr long R1LEN = ((long)MS * 3072 + 1) / 2;  // 7,090,176 floats
  float* scb = R1 + R1LEN;
  // region R2: q/k hi/lo (transient) -> later x1n_bf + attn_bf
  unsigned short* qh = (unsigned short*)(scb + SCL);
  unsigned short* ql = qh + MPD;
  unsigned short* kh = ql + MPD;
  unsigned short* kl = kh + MPD;
  unsigned short* x1n_bf  = qh;          // NSD shorts, live after scores dead
  unsigned short* attn_bf = qh + NSD;    // NSD shorts
  // weights (bf16)
  unsigned short* wqk_hi  = kl + MPD;                   // [1536][768]
  unsigned short* wqk_lo  = wqk_hi + (long)1536 * 768;
  unsigned short* wqkv_t  = wqk_lo + (long)1536 * 768;  // [2304][768]
  unsigned short* wproj_t = wqkv_t + (long)2304 * 768;  // [768][768]
  unsigned short* wm1_t   = wproj_t + (long)768 * 768;  // [3072][768]
  unsigned short* wm2_t   = wm1_t + (long)3072 * 768;   // [768][3072]

  // weight prep
  transpose_hl<<<dim3(24, 24), 256, 0, stream>>>(wq, wqk_hi, wqk_lo, 768, 768, 0);
  transpose_hl<<<dim3(24, 24), 256, 0, stream>>>(wk, wqk_hi, wqk_lo, 768, 768, 768);
  transpose_hl<<<dim3(72, 24), 256, 0, stream>>>(wqkv, wqkv_t, nullptr, 768, 2304, 0);
  transpose_hl<<<dim3(24, 24), 256, 0, stream>>>(wproj, wproj_t, nullptr, 768, 768, 0);
  transpose_hl<<<dim3(96, 24), 256, 0, stream>>>(wm1, wm1_t, nullptr, 768, 3072, 0);
  transpose_hl<<<dim3(24, 96), 256, 0, stream>>>(wm2, wm2_t, nullptr, 3072, 768, 0);

  // 1. LN1 -> bf16 hi/lo
  ln_rows_bf<true><<<MS, 256, 0, stream>>>(x, g1, b1, xn_hi, xn_lo);
  // 2. routing projections (bf16x3 emulated fp32), q|k fused
  gemm_rproj<<<dim3(1536 / 128, MP / 128), 256, 0, stream>>>(
      xn_hi, xn_lo, wqk_hi, wqk_lo, bq, bk, qbuf, kbuf);
  // 3. l2norm -> hi/lo
  l2norm_hl<<<MP, 256, 0, stream>>>(qbuf, qh, ql);
  l2norm_hl<<<MP, 256, 0, stream>>>(kbuf, kh, kl);
  // 4. routing scores (bf16x3, batched, fused pos/diag/x10)
  gemm_scores<<<dim3(5, 5, B_), 256, 0, stream>>>(qh, ql, kh, kl, pos, scb);
  // 5. top-32 + log-softmax
  topk_route<<<MP, 64, 0, stream>>>(scb, routes, logw);
  // 6. fused QKV projection (bf16 MFMA) -> (B,H,S,HD) fp32
  gemm_bf16<BEPI_QKV><<<dim3(2304 / 128, (MS + 127) / 128), 256, 0, stream>>>(
      xn_hi, wqkv_t, bqkv, nullptr, nullptr, nullptr, MS, 2304, D_, Qb, Kb, Vb);
  // 7. attention (fp32 compute, bf16 out)
  cls_attn<<<B_ * H_, 256, 0, stream>>>(Qb, Kb, Vb, attn_bf);
  patch_attn<<<MP, 256, 0, stream>>>(Qb, Kb, Vb, routes, logw, attn_bf);
  // 8. output projection + residual
  gemm_bf16<BEPI_ADD><<<dim3(D_ / 128, (MS + 127) / 128), 256, 0, stream>>>(
      attn_bf, wproj_t, bproj, x, x1, nullptr, MS, D_, D_, nullptr, nullptr, nullptr);
  // 9. LN2 + MLP
  ln_rows_bf<false><<<MS, 256, 0, stream>>>(x1, g2, b2, x1n_bf, nullptr);
  gemm_bf16<BEPI_GELU><<<dim3(3072 / 128, (MS + 127) / 128), 256, 0, stream>>>(
      x1n_bf, wm1_t, bm1, nullptr, nullptr, h_bf, MS, 3072, D_, nullptr, nullptr, nullptr);
  gemm_bf16<BEPI_ADD><<<dim3(D_ / 128, (MS + 127) / 128), 256, 0, stream>>>(
      h_bf, wm2_t, bm2, x1, out, nullptr, MS, D_, 3072, nullptr, nullptr, nullptr);
}

// Round 5
// 603.368 us; speedup vs baseline: 2.4673x; 1.1490x over previous
//
#include <hip/hip_runtime.h>
#include <math.h>

// ---- problem constants ----
#define B_  8
#define S_  577
#define D_  768
#define H_  12
#define P_  576
#define KW_ 32
#define HD_ 64
constexpr int   MS       = B_ * S_;   // 4616
constexpr int   MP       = B_ * P_;   // 4608
constexpr float SCALE_   = 0.125f;
constexpr float INV_TEMP = 10.0f;

typedef __attribute__((ext_vector_type(8))) short bf16x8;
typedef __attribute__((ext_vector_type(4))) float f32x4;

__device__ __forceinline__ unsigned short f2bf(float f) {
  unsigned int x = __float_as_uint(f);
  x += 0x7fffu + ((x >> 16) & 1u);  // RNE
  return (unsigned short)(x >> 16);
}
__device__ __forceinline__ float bf2f(unsigned short h) {
  return __uint_as_float((unsigned int)h << 16);
}
__device__ __forceinline__ void gl_lds16(const unsigned short* g,
                                         unsigned short* l) {
  __builtin_amdgcn_global_load_lds(
      (const __attribute__((address_space(1))) void*)g,
      (__attribute__((address_space(3))) void*)l, 16, 0, 0);
}
// unpack 8 bf16 -> 8 f32 (2 bit-ops per pair)
__device__ __forceinline__ void unpack8(bf16x8 v, float* f) {
  union { bf16x8 v8; unsigned int w[4]; } u;
  u.v8 = v;
#pragma unroll
  for (int i = 0; i < 4; ++i) {
    f[2 * i]     = __uint_as_float(u.w[i] << 16);
    f[2 * i + 1] = __uint_as_float(u.w[i] & 0xffff0000u);
  }
}

// ============================================================
// LayerNorm -> bf16 hi (+ optional lo). One block per row.
// ============================================================
template <bool LO>
__global__ __launch_bounds__(256) void ln_rows_bf(
    const float* __restrict__ X, const float* __restrict__ g,
    const float* __restrict__ bta, unsigned short* __restrict__ Yh,
    unsigned short* __restrict__ Yl) {
  const int r = blockIdx.x, tid = threadIdx.x;
  const float* row = X + (long)r * D_;
  float v[3];
  float s = 0.f, sq = 0.f;
#pragma unroll
  for (int t = 0; t < 3; ++t) {
    v[t] = row[tid + t * 256];
    s += v[t];
    sq = fmaf(v[t], v[t], sq);
  }
#pragma unroll
  for (int off = 32; off; off >>= 1) {
    s  += __shfl_xor(s, off);
    sq += __shfl_xor(sq, off);
  }
  __shared__ float rs[4], rq[4];
  if ((tid & 63) == 0) { rs[tid >> 6] = s; rq[tid >> 6] = sq; }
  __syncthreads();
  s  = rs[0] + rs[1] + rs[2] + rs[3];
  sq = rq[0] + rq[1] + rq[2] + rq[3];
  const float m   = s * (1.f / D_);
  const float var = sq * (1.f / D_) - m * m;
  const float inv = rsqrtf(var + 1e-5f);
#pragma unroll
  for (int t = 0; t < 3; ++t) {
    const int c = tid + t * 256;
    const float y = (v[t] - m) * inv * g[c] + bta[c];
    const unsigned short h = f2bf(y);
    Yh[(long)r * D_ + c] = h;
    if (LO) Yl[(long)r * D_ + c] = f2bf(y - bf2f(h));
  }
}

// ============================================================
// l2-normalize fp32 row -> bf16 hi/lo
// ============================================================
__global__ __launch_bounds__(256) void l2norm_hl(
    const float* __restrict__ X, unsigned short* __restrict__ Yh,
    unsigned short* __restrict__ Yl) {
  const int r = blockIdx.x, tid = threadIdx.x;
  const float* row = X + (long)r * D_;
  float v[3];
  float sq = 0.f;
#pragma unroll
  for (int t = 0; t < 3; ++t) {
    v[t] = row[tid + t * 256];
    sq = fmaf(v[t], v[t], sq);
  }
#pragma unroll
  for (int off = 32; off; off >>= 1) sq += __shfl_xor(sq, off);
  __shared__ float rq[4];
  if ((tid & 63) == 0) rq[tid >> 6] = sq;
  __syncthreads();
  sq = rq[0] + rq[1] + rq[2] + rq[3];
  const float sc = 1.f / fmaxf(sqrtf(sq), 1e-12f);
#pragma unroll
  for (int t = 0; t < 3; ++t) {
    const float y = v[t] * sc;
    const unsigned short h = f2bf(y);
    Yh[(long)r * D_ + tid + t * 256] = h;
    Yl[(long)r * D_ + tid + t * 256] = f2bf(y - bf2f(h));
  }
}

// ============================================================
// weight transpose fp32[K][N] -> bf16 [rowoff+N][K] hi (+lo)
// ============================================================
__global__ __launch_bounds__(256) void transpose_hl(
    const float* __restrict__ W, unsigned short* __restrict__ Th,
    unsigned short* __restrict__ Tl, int K, int N, int rowoff) {
  __shared__ float t[32][33];
  const int tx = threadIdx.x & 31, ty = threadIdx.x >> 5;
  const int n0 = blockIdx.x * 32, k0 = blockIdx.y * 32;
#pragma unroll
  for (int i = ty; i < 32; i += 8)
    t[i][tx] = W[(long)(k0 + i) * N + n0 + tx];
  __syncthreads();
#pragma unroll
  for (int i = ty; i < 32; i += 8) {
    const float w = t[tx][i];
    const unsigned short h = f2bf(w);
    const long o = (long)(rowoff + n0 + i) * K + k0 + tx;
    Th[o] = h;
    if (Tl) Tl[o] = f2bf(w - bf2f(h));
  }
}

// ============================================================
// bf16 MFMA GEMM (smooth path): C = A @ Wt^T + bias, 128x128x32
// ============================================================
enum { BEPI_QKV = 0, BEPI_ADD = 1, BEPI_GELU = 2 };

template <int EPI>
__global__ __launch_bounds__(256, 2) void gemm_bf16(
    const unsigned short* __restrict__ A, const unsigned short* __restrict__ Wt,
    const float* __restrict__ bias, const float* __restrict__ R,
    float* __restrict__ C, unsigned short* __restrict__ Cbf,
    int M, int N, int K,
    unsigned short* __restrict__ Qb, unsigned short* __restrict__ Kb,
    unsigned short* __restrict__ Vb) {
  constexpr int BK = 32;
  __shared__ __align__(16) unsigned short ldsA[128 * BK];
  __shared__ __align__(16) unsigned short ldsB[128 * BK];
  const int tid = threadIdx.x, wave = tid >> 6, lane = tid & 63;
  const int wr = wave >> 1, wc = wave & 1;
  const int l16 = lane & 15, l4 = lane >> 4;
  const int bn = blockIdx.x, bm = blockIdx.y;
  const int row0 = bm * 128;

  f32x4 acc[4][4];
#pragma unroll
  for (int i = 0; i < 4; ++i)
#pragma unroll
    for (int j = 0; j < 4; ++j) acc[i][j] = (f32x4){0.f, 0.f, 0.f, 0.f};

  const int c0 = tid, c1 = tid + 256;
  int ar0 = row0 + (c0 >> 2); if (ar0 > M - 1) ar0 = M - 1;
  int ar1 = row0 + (c1 >> 2); if (ar1 > M - 1) ar1 = M - 1;
  const unsigned short* ga0 = A + (long)ar0 * K + ((c0 & 3) << 3);
  const unsigned short* ga1 = A + (long)ar1 * K + ((c1 & 3) << 3);
  const unsigned short* gb0 = Wt + (long)(bn * 128 + (c0 >> 2)) * K + ((c0 & 3) << 3);
  const unsigned short* gb1 = Wt + (long)(bn * 128 + (c1 >> 2)) * K + ((c1 & 3) << 3);

  for (int k0 = 0; k0 < K; k0 += BK) {
    __syncthreads();
    gl_lds16(ga0 + k0, ldsA + c0 * 8);
    gl_lds16(ga1 + k0, ldsA + c1 * 8);
    gl_lds16(gb0 + k0, ldsB + c0 * 8);
    gl_lds16(gb1 + k0, ldsB + c1 * 8);
    __syncthreads();
    bf16x8 af[4], bfr[4];
#pragma unroll
    for (int i = 0; i < 4; ++i)
      af[i] = *(const bf16x8*)(ldsA + (wr * 64 + i * 16 + l16) * BK + l4 * 8);
#pragma unroll
    for (int j = 0; j < 4; ++j)
      bfr[j] = *(const bf16x8*)(ldsB + (wc * 64 + j * 16 + l16) * BK + l4 * 8);
#pragma unroll
    for (int i = 0; i < 4; ++i)
#pragma unroll
      for (int j = 0; j < 4; ++j)
        acc[i][j] = __builtin_amdgcn_mfma_f32_16x16x32_bf16(af[i], bfr[j],
                                                            acc[i][j], 0, 0, 0);
  }

#pragma unroll
  for (int j = 0; j < 4; ++j) {
    const int gcol = bn * 128 + wc * 64 + j * 16 + l16;
    const float bb = bias[gcol];
#pragma unroll
    for (int i = 0; i < 4; ++i) {
      const int grow0 = row0 + wr * 64 + i * 16 + l4 * 4;
#pragma unroll
      for (int r = 0; r < 4; ++r) {
        const int grow = grow0 + r;
        if (grow >= M) continue;
        float v = acc[i][j][r] + bb;
        if (EPI == BEPI_GELU) {
          v = 0.5f * v * (1.f + erff(v * 0.70710678118654752f));
          Cbf[(long)grow * N + gcol] = f2bf(v);
        } else if (EPI == BEPI_ADD) {
          C[(long)grow * N + gcol] = v + R[(long)grow * N + gcol];
        } else {  // BEPI_QKV: scatter bf16 to (B,H,S,HD)
          const int t   = gcol / (H_ * HD_);
          const int rem = gcol - t * (H_ * HD_);
          const int h   = rem >> 6;
          const int d   = rem & 63;
          const int b   = grow / S_;
          const int ss  = grow - b * S_;
          unsigned short* dst = (t == 0 ? Qb : (t == 1 ? Kb : Vb));
          dst[(((long)(b * H_ + h) * S_ + ss) << 6) + d] = f2bf(v);
        }
      }
    }
  }
}

// ============================================================
// routing projection: bf16x3 emulated-fp32 GEMM
// ============================================================
__global__ __launch_bounds__(256, 2) void gemm_rproj(
    const unsigned short* __restrict__ Ahi, const unsigned short* __restrict__ Alo,
    const unsigned short* __restrict__ Whi, const unsigned short* __restrict__ Wlo,
    const float* __restrict__ bq, const float* __restrict__ bk,
    float* __restrict__ qout, float* __restrict__ kout) {
  constexpr int BK = 32, K = D_;
  __shared__ __align__(16) unsigned short ldsA[128 * BK];
  __shared__ __align__(16) unsigned short ldsB[128 * BK];
  const int tid = threadIdx.x, wave = tid >> 6, lane = tid & 63;
  const int wr = wave >> 1, wc = wave & 1;
  const int l16 = lane & 15, l4 = lane >> 4;
  const int bn = blockIdx.x, bm = blockIdx.y;
  const int row0 = bm * 128;

  f32x4 acc[4][4];
#pragma unroll
  for (int i = 0; i < 4; ++i)
#pragma unroll
    for (int j = 0; j < 4; ++j) acc[i][j] = (f32x4){0.f, 0.f, 0.f, 0.f};

  const int c0 = tid, c1 = tid + 256;
  const int r0 = row0 + (c0 >> 2), r1 = row0 + (c1 >> 2);
  const long aoff0 = (long)(r0 + r0 / P_ + 1) * K + ((c0 & 3) << 3);
  const long aoff1 = (long)(r1 + r1 / P_ + 1) * K + ((c1 & 3) << 3);
  const long boff0 = (long)(bn * 128 + (c0 >> 2)) * K + ((c0 & 3) << 3);
  const long boff1 = (long)(bn * 128 + (c1 >> 2)) * K + ((c1 & 3) << 3);

  for (int ph = 0; ph < 3; ++ph) {
    const unsigned short* As = (ph < 2) ? Ahi : Alo;
    const unsigned short* Bs = (ph == 1) ? Wlo : Whi;
    for (int k0 = 0; k0 < K; k0 += BK) {
      __syncthreads();
      gl_lds16(As + aoff0 + k0, ldsA + c0 * 8);
      gl_lds16(As + aoff1 + k0, ldsA + c1 * 8);
      gl_lds16(Bs + boff0 + k0, ldsB + c0 * 8);
      gl_lds16(Bs + boff1 + k0, ldsB + c1 * 8);
      __syncthreads();
      bf16x8 af[4], bfr[4];
#pragma unroll
      for (int i = 0; i < 4; ++i)
        af[i] = *(const bf16x8*)(ldsA + (wr * 64 + i * 16 + l16) * BK + l4 * 8);
#pragma unroll
      for (int j = 0; j < 4; ++j)
        bfr[j] = *(const bf16x8*)(ldsB + (wc * 64 + j * 16 + l16) * BK + l4 * 8);
#pragma unroll
      for (int i = 0; i < 4; ++i)
#pragma unroll
        for (int j = 0; j < 4; ++j)
          acc[i][j] = __builtin_amdgcn_mfma_f32_16x16x32_bf16(af[i], bfr[j],
                                                              acc[i][j], 0, 0, 0);
    }
  }

#pragma unroll
  for (int j = 0; j < 4; ++j) {
    const int gcol = bn * 128 + wc * 64 + j * 16 + l16;
    const float bb = (gcol < D_) ? bq[gcol] : bk[gcol - D_];
#pragma unroll
    for (int i = 0; i < 4; ++i) {
      const int grow0 = row0 + wr * 64 + i * 16 + l4 * 4;
#pragma unroll
      for (int r = 0; r < 4; ++r) {
        const int grow = grow0 + r;
        const float v = acc[i][j][r] + bb;
        if (gcol < D_) qout[(long)grow * D_ + gcol] = v;
        else           kout[(long)grow * D_ + gcol - D_] = v;
      }
    }
  }
}

// ============================================================
// routing scores: batched bf16x3 NT GEMM + pos bias + diag + x10
// ============================================================
__global__ __launch_bounds__(256, 2) void gemm_scores(
    const unsigned short* __restrict__ Qh, const unsigned short* __restrict__ Ql,
    const unsigned short* __restrict__ Kh, const unsigned short* __restrict__ Kl,
    const float* __restrict__ pos, float* __restrict__ sc) {
  constexpr int BK = 32, K = D_;
  __shared__ __align__(16) unsigned short ldsA[128 * BK];
  __shared__ __align__(16) unsigned short ldsB[128 * BK];
  const int tid = threadIdx.x, wave = tid >> 6, lane = tid & 63;
  const int wr = wave >> 1, wc = wave & 1;
  const int l16 = lane & 15, l4 = lane >> 4;
  const int bn = blockIdx.x, bm = blockIdx.y, b = blockIdx.z;
  const long base = (long)b * P_ * K;
  const int row0 = bm * 128;

  f32x4 acc[4][4];
#pragma unroll
  for (int i = 0; i < 4; ++i)
#pragma unroll
    for (int j = 0; j < 4; ++j) acc[i][j] = (f32x4){0.f, 0.f, 0.f, 0.f};

  const int c0 = tid, c1 = tid + 256;
  int r0 = row0 + (c0 >> 2); if (r0 > P_ - 1) r0 = P_ - 1;
  int r1 = row0 + (c1 >> 2); if (r1 > P_ - 1) r1 = P_ - 1;
  int n0 = bn * 128 + (c0 >> 2); if (n0 > P_ - 1) n0 = P_ - 1;
  int n1 = bn * 128 + (c1 >> 2); if (n1 > P_ - 1) n1 = P_ - 1;
  const long aoff0 = base + (long)r0 * K + ((c0 & 3) << 3);
  const long aoff1 = base + (long)r1 * K + ((c1 & 3) << 3);
  const long boff0 = base + (long)n0 * K + ((c0 & 3) << 3);
  const long boff1 = base + (long)n1 * K + ((c1 & 3) << 3);

  for (int ph = 0; ph < 3; ++ph) {
    const unsigned short* As = (ph < 2) ? Qh : Ql;
    const unsigned short* Bs = (ph == 1) ? Kl : Kh;
    for (int k0 = 0; k0 < K; k0 += BK) {
      __syncthreads();
      gl_lds16(As + aoff0 + k0, ldsA + c0 * 8);
      gl_lds16(As + aoff1 + k0, ldsA + c1 * 8);
      gl_lds16(Bs + boff0 + k0, ldsB + c0 * 8);
      gl_lds16(Bs + boff1 + k0, ldsB + c1 * 8);
      __syncthreads();
      bf16x8 af[4], bfr[4];
#pragma unroll
      for (int i = 0; i < 4; ++i)
        af[i] = *(const bf16x8*)(ldsA + (wr * 64 + i * 16 + l16) * BK + l4 * 8);
#pragma unroll
      for (int j = 0; j < 4; ++j)
        bfr[j] = *(const bf16x8*)(ldsB + (wc * 64 + j * 16 + l16) * BK + l4 * 8);
#pragma unroll
      for (int i = 0; i < 4; ++i)
#pragma unroll
        for (int j = 0; j < 4; ++j)
          acc[i][j] = __builtin_amdgcn_mfma_f32_16x16x32_bf16(af[i], bfr[j],
                                                              acc[i][j], 0, 0, 0);
    }
  }

#pragma unroll
  for (int j = 0; j < 4; ++j) {
    const int gj = bn * 128 + wc * 64 + j * 16 + l16;
    if (gj >= P_) continue;
#pragma unroll
    for (int i = 0; i < 4; ++i) {
      const int grow0 = row0 + wr * 64 + i * 16 + l4 * 4;
#pragma unroll
      for (int r = 0; r < 4; ++r) {
        const int gi = grow0 + r;
        if (gi >= P_) continue;
        const float s = (gi == gj) ? -1e9f : acc[i][j][r] + pos[(long)gi * P_ + gj];
        sc[((long)b * P_ + gi) * P_ + gj] = s * INV_TEMP;
      }
    }
  }
}

// ============================================================
// top-32 + log-softmax weights. One wave per row.
// ============================================================
__global__ __launch_bounds__(64) void topk_route(
    const float* __restrict__ sc, int* __restrict__ routes,
    float* __restrict__ logw) {
  const int row = blockIdx.x, lane = threadIdx.x;
  const float* srow = sc + (long)row * P_;
  float v[9];
#pragma unroll
  for (int t = 0; t < 9; ++t) v[t] = srow[lane + (t << 6)];
  float selv = 0.f;
  int   selj = 0;
  for (int it = 0; it < KW_; ++it) {
    float bv = -3.0e38f;
    int   bj = 0x7fffffff;
#pragma unroll
    for (int t = 0; t < 9; ++t) {
      if (v[t] > bv) { bv = v[t]; bj = lane + (t << 6); }
    }
#pragma unroll
    for (int off = 32; off; off >>= 1) {
      const float ov = __shfl_xor(bv, off);
      const int   oj = __shfl_xor(bj, off);
      if (ov > bv || (ov == bv && oj < bj)) { bv = ov; bj = oj; }
    }
    if (lane == it) { selv = bv; selj = bj; }
    if ((bj & 63) == lane) v[bj >> 6] = -3.0e38f;
  }
  const float x = (lane < KW_) ? selv : -3.0e38f;
  float m = x;
#pragma unroll
  for (int off = 16; off; off >>= 1) m = fmaxf(m, __shfl_xor(m, off));
  const float e = expf(x - m);
  float s = e;
#pragma unroll
  for (int off = 16; off; off >>= 1) s += __shfl_xor(s, off);
  const float lw = fmaxf(x - m - logf(s), -10.0f);
  if (lane < KW_) {
    routes[(long)row * KW_ + lane] = selj;
    logw[(long)row * KW_ + lane]   = lw;
  }
}

// ============================================================
// patch attention v2: block = (b, h, p-half); K/V head-slice
// staged in 147KB LDS (bf16, XOR-swizzled). 1024 thr = 16 waves,
// each wave owns 18 query rows. Lane layout: 64 = 8 keys x 8 chunks.
// ============================================================
__global__ __launch_bounds__(1024, 1) void patch_attn2(
    const unsigned short* __restrict__ Qb, const unsigned short* __restrict__ Kb,
    const unsigned short* __restrict__ Vb, const int* __restrict__ routes,
    const float* __restrict__ logw, unsigned short* __restrict__ attn) {
  __shared__ __align__(16) unsigned short ldsK[P_ * HD_];  // 73728 B
  __shared__ __align__(16) unsigned short ldsV[P_ * HD_];  // 73728 B
  const int tid = threadIdx.x;
  const int b = blockIdx.x & 7;
  const int rest = blockIdx.x >> 3;
  const int phalf = rest & 1;
  const int h = rest >> 1;
  const long hb = ((long)(b * H_ + h) * S_) << 6;  // ushort offset of (b,h)

  // ---- stage K,V rows s=1..576 into swizzled LDS ----
  const unsigned short* kg = Kb + hb + HD_;  // skip cls row
  const unsigned short* vg = Vb + hb + HD_;
#pragma unroll
  for (int c = tid; c < P_ * 8; c += 1024) {
    const int r = c >> 3, i = c & 7;
    const int lo = r * 64 + ((i * 8) ^ ((r & 7) << 3));
    *(bf16x8*)(ldsK + lo) = *(const bf16x8*)(kg + c * 8);
    *(bf16x8*)(ldsV + lo) = *(const bf16x8*)(vg + c * 8);
  }
  __syncthreads();

  const int wave = tid >> 6, lane = tid & 63;
  const int g = lane >> 3, ch = lane & 7;
  const int p0 = phalf * 288;

  for (int p = p0 + wave; p < p0 + 288; p += 16) {
    const int s = p + 1;
    const long bp32 = ((long)(b * P_ + p)) << 5;
    // Q chunk for this lane's dim range
    float qf[8];
    unpack8(*(const bf16x8*)(Qb + hb + ((long)s << 6) + ch * 8), qf);
    // ---- scores for 32 routed keys (4 iters x 8 keys) ----
    int   rk[4];
    float sc4[4];
    float m = -3.0e38f;
#pragma unroll
    for (int it = 0; it < 4; ++it) {
      const int key = it * 8 + g;
      rk[it] = routes[bp32 + key];
      float kf[8];
      unpack8(*(const bf16x8*)(ldsK + rk[it] * 64 +
                               ((ch * 8) ^ ((rk[it] & 7) << 3))), kf);
      float d0 = 0.f;
#pragma unroll
      for (int d = 0; d < 8; ++d) d0 = fmaf(qf[d], kf[d], d0);
      d0 += __shfl_xor(d0, 1);
      d0 += __shfl_xor(d0, 2);
      d0 += __shfl_xor(d0, 4);
      sc4[it] = fmaf(d0, SCALE_, logw[bp32 + key]);
      m = fmaxf(m, sc4[it]);
    }
    m = fmaxf(m, __shfl_xor(m, 8));
    m = fmaxf(m, __shfl_xor(m, 16));
    m = fmaxf(m, __shfl_xor(m, 32));
    float e4[4], lsum = 0.f;
#pragma unroll
    for (int it = 0; it < 4; ++it) {
      e4[it] = __expf(sc4[it] - m);
      lsum += e4[it];
    }
    lsum += __shfl_xor(lsum, 8);
    lsum += __shfl_xor(lsum, 16);
    lsum += __shfl_xor(lsum, 32);
    // ---- V accumulate (weight already lane-local) ----
    float facc[8];
#pragma unroll
    for (int d = 0; d < 8; ++d) facc[d] = 0.f;
#pragma unroll
    for (int it = 0; it < 4; ++it) {
      float vf[8];
      unpack8(*(const bf16x8*)(ldsV + rk[it] * 64 +
                               ((ch * 8) ^ ((rk[it] & 7) << 3))), vf);
#pragma unroll
      for (int d = 0; d < 8; ++d) facc[d] = fmaf(e4[it], vf[d], facc[d]);
    }
#pragma unroll
    for (int off = 8; off <= 32; off <<= 1)
#pragma unroll
      for (int d = 0; d < 8; ++d) facc[d] += __shfl_xor(facc[d], off);
    const float inv = 1.f / lsum;
    if (lane < 8) {
      union { bf16x8 v8; unsigned short u[8]; } o;
#pragma unroll
      for (int d = 0; d < 8; ++d) o.u[d] = f2bf(facc[d] * inv);
      *(bf16x8*)(attn + ((long)b * S_ + s) * D_ + h * HD_ + ch * 8) = o.v8;
    }
  }
}

// ============================================================
// cls-token attention (bf16 in/out)
// ============================================================
__global__ __launch_bounds__(256) void cls_attn(
    const unsigned short* __restrict__ Qb, const unsigned short* __restrict__ Kb,
    const unsigned short* __restrict__ Vb, unsigned short* __restrict__ attn) {
  const int bh = blockIdx.x;
  const int b = bh / H_, h = bh - b * H_;
  const int tid = threadIdx.x;
  __shared__ float qs[HD_];
  __shared__ float ssh[S_];
  __shared__ float redm[4], reds[4];
  __shared__ float osh[4][HD_];
  const unsigned short* Qrow  = Qb + (long)bh * S_ * HD_;
  const unsigned short* Kbase = Kb + (long)bh * S_ * HD_;
  const unsigned short* Vbase = Vb + (long)bh * S_ * HD_;
  if (tid < HD_) qs[tid] = bf2f(Qrow[tid]);
  __syncthreads();
  float lmax = -3.0e38f;
  for (int j = tid; j < S_; j += 256) {
    const unsigned short* kr = Kbase + (long)j * HD_;
    float dot = 0.f;
#pragma unroll
    for (int dd = 0; dd < HD_; dd += 8) {
      float kf[8];
      unpack8(*(const bf16x8*)(kr + dd), kf);
#pragma unroll
      for (int t = 0; t < 8; ++t) dot = fmaf(kf[t], qs[dd + t], dot);
    }
    dot *= SCALE_;
    ssh[j] = dot;
    lmax = fmaxf(lmax, dot);
  }
#pragma unroll
  for (int off = 32; off; off >>= 1) lmax = fmaxf(lmax, __shfl_xor(lmax, off));
  if ((tid & 63) == 0) redm[tid >> 6] = lmax;
  __syncthreads();
  const float m = fmaxf(fmaxf(redm[0], redm[1]), fmaxf(redm[2], redm[3]));
  float lsum = 0.f;
  for (int j = tid; j < S_; j += 256) {
    const float e = expf(ssh[j] - m);
    ssh[j] = e;
    lsum += e;
  }
#pragma unroll
  for (int off = 32; off; off >>= 1) lsum += __shfl_xor(lsum, off);
  if ((tid & 63) == 0) reds[tid >> 6] = lsum;
  __syncthreads();
  const float inv = 1.f / (reds[0] + reds[1] + reds[2] + reds[3]);
  const int d = tid & 63, qt = tid >> 6;
  float acc = 0.f;
  for (int j = qt; j < S_; j += 4)
    acc = fmaf(ssh[j], bf2f(Vbase[((long)j << 6) + d]), acc);
  osh[qt][d] = acc;
  __syncthreads();
  if (tid < HD_) {
    const float o = (osh[0][tid] + osh[1][tid] + osh[2][tid] + osh[3][tid]) * inv;
    attn[(long)b * S_ * D_ + h * HD_ + tid] = f2bf(o);
  }
}

// ============================================================
// host-side launch
// ============================================================
extern "C" void kernel_launch(void* const* d_in, const int* in_sizes, int n_in,
                              void* d_out, int out_size, void* d_ws,
                              size_t ws_size, hipStream_t stream) {
  const float* x     = (const float*)d_in[0];
  const float* g1    = (const float*)d_in[1];
  const float* b1    = (const float*)d_in[2];
  const float* wq    = (const float*)d_in[3];
  const float* bq    = (const float*)d_in[4];
  const float* wk    = (const float*)d_in[5];
  const float* bk    = (const float*)d_in[6];
  const float* pos   = (const float*)d_in[7];
  const float* wqkv  = (const float*)d_in[8];
  const float* bqkv  = (const float*)d_in[9];
  const float* wproj = (const float*)d_in[10];
  const float* bproj = (const float*)d_in[11];
  const float* g2    = (const float*)d_in[12];
  const float* b2    = (const float*)d_in[13];
  const float* wm1   = (const float*)d_in[14];
  const float* bm1   = (const float*)d_in[15];
  const float* wm2   = (const float*)d_in[16];
  const float* bm2   = (const float*)d_in[17];
  float* out = (float*)d_out;

  constexpr long NSD = (long)MS * D_;       // 3,545,088 (== B*H*S*HD)
  constexpr long MPD = (long)MP * D_;       // 3,538,944
  constexpr long SCL = (long)B_ * P_ * P_;  // 2,654,208

  unsigned short* xn_hi = (unsigned short*)d_ws;
  unsigned short* xn_lo = xn_hi + NSD;
  float* x1 = (float*)(xn_lo + NSD);
  unsigned short* Qb = (unsigned short*)(x1 + NSD);
  unsigned short* Kb = Qb + NSD;
  unsigned short* Vb = Kb + NSD;
  int*   routes = (int*)(Vb + NSD);
  float* logw   = (float*)(routes + (long)MP * KW_);
  // region R1: qbuf+kbuf (fp32, transient) -> later h_bf (bf16 MLP hidden)
  float* R1   = logw + (long)MP * KW_;
  float* qbuf = R1;
  float* kbuf = qbuf + MPD;
  unsigned short* h_bf = (unsigned short*)R1;        // 4616*3072 shorts
  constexpr long R1LEN = ((long)MS * 3072 + 1) / 2;  // floats
  float* scb = R1 + R1LEN;
  // region R2: q/k hi/lo (transient) -> later x1n_bf + attn_bf
  unsigned short* qh = (unsigned short*)(scb + SCL);
  unsigned short* ql = qh + MPD;
  unsigned short* kh = ql + MPD;
  unsigned short* kl = kh + MPD;
  unsigned short* x1n_bf  = qh;        // NSD shorts, live after scores dead
  unsigned short* attn_bf = qh + NSD;  // NSD shorts
  // weights (bf16)
  unsigned short* wqk_hi  = kl + MPD;                   // [1536][768]
  unsigned short* wqk_lo  = wqk_hi + (long)1536 * 768;
  unsigned short* wqkv_t  = wqk_lo + (long)1536 * 768;  // [2304][768]
  unsigned short* wproj_t = wqkv_t + (long)2304 * 768;  // [768][768]
  unsigned short* wm1_t   = wproj_t + (long)768 * 768;  // [3072][768]
  unsigned short* wm2_t   = wm1_t + (long)3072 * 768;   // [768][3072]

  // weight prep
  transpose_hl<<<dim3(24, 24), 256, 0, stream>>>(wq, wqk_hi, wqk_lo, 768, 768, 0);
  transpose_hl<<<dim3(24, 24), 256, 0, stream>>>(wk, wqk_hi, wqk_lo, 768, 768, 768);
  transpose_hl<<<dim3(72, 24), 256, 0, stream>>>(wqkv, wqkv_t, nullptr, 768, 2304, 0);
  transpose_hl<<<dim3(24, 24), 256, 0, stream>>>(wproj, wproj_t, nullptr, 768, 768, 0);
  transpose_hl<<<dim3(96, 24), 256, 0, stream>>>(wm1, wm1_t, nullptr, 768, 3072, 0);
  transpose_hl<<<dim3(24, 96), 256, 0, stream>>>(wm2, wm2_t, nullptr, 3072, 768, 0);

  // 1. LN1 -> bf16 hi/lo
  ln_rows_bf<true><<<MS, 256, 0, stream>>>(x, g1, b1, xn_hi, xn_lo);
  // 2. routing projections (bf16x3 emulated fp32), q|k fused
  gemm_rproj<<<dim3(1536 / 128, MP / 128), 256, 0, stream>>>(
      xn_hi, xn_lo, wqk_hi, wqk_lo, bq, bk, qbuf, kbuf);
  // 3. l2norm -> hi/lo
  l2norm_hl<<<MP, 256, 0, stream>>>(qbuf, qh, ql);
  l2norm_hl<<<MP, 256, 0, stream>>>(kbuf, kh, kl);
  // 4. routing scores (bf16x3, batched, fused pos/diag/x10)
  gemm_scores<<<dim3(5, 5, B_), 256, 0, stream>>>(qh, ql, kh, kl, pos, scb);
  // 5. top-32 + log-softmax
  topk_route<<<MP, 64, 0, stream>>>(scb, routes, logw);
  // 6. fused QKV projection (bf16 MFMA) -> (B,H,S,HD) bf16
  gemm_bf16<BEPI_QKV><<<dim3(2304 / 128, (MS + 127) / 128), 256, 0, stream>>>(
      xn_hi, wqkv_t, bqkv, nullptr, nullptr, nullptr, MS, 2304, D_, Qb, Kb, Vb);
  // 7. attention (bf16 in, fp32 compute, bf16 out)
  cls_attn<<<B_ * H_, 256, 0, stream>>>(Qb, Kb, Vb, attn_bf);
  patch_attn2<<<192, 1024, 0, stream>>>(Qb, Kb, Vb, routes, logw, attn_bf);
  // 8. output projection + residual
  gemm_bf16<BEPI_ADD><<<dim3(D_ / 128, (MS + 127) / 128), 256, 0, stream>>>(
      attn_bf, wproj_t, bproj, x, x1, nullptr, MS, D_, D_, nullptr, nullptr,
      nullptr);
  // 9. LN2 + MLP
  ln_rows_bf<false><<<MS, 256, 0, stream>>>(x1, g2, b2, x1n_bf, nullptr);
  gemm_bf16<BEPI_GELU><<<dim3(3072 / 128, (MS + 127) / 128), 256, 0, stream>>>(
      x1n_bf, wm1_t, bm1, nullptr, nullptr, h_bf, MS, 3072, D_, nullptr,
      nullptr, nullptr);
  gemm_bf16<BEPI_ADD><<<dim3(D_ / 128, (MS + 127) / 128), 256, 0, stream>>>(
      h_bf, wm2_t, bm2, x1, out, nullptr, MS, D_, 3072, nullptr, nullptr,
      nullptr);
}

// Round 7
// 546.077 us; speedup vs baseline: 2.7262x; 1.1049x over previous
//
#include <hip/hip_runtime.h>
#include <math.h>

// ---- problem constants ----
#define B_  8
#define S_  577
#define D_  768
#define H_  12
#define P_  576
#define KW_ 32
#define HD_ 64
constexpr int   MS       = B_ * S_;   // 4616
constexpr int   MP       = B_ * P_;   // 4608
constexpr float SCALE_   = 0.125f;
constexpr float INV_TEMP = 10.0f;

typedef __attribute__((ext_vector_type(8))) short bf16x8;
typedef __attribute__((ext_vector_type(4))) float f32x4;

__device__ __forceinline__ unsigned short f2bf(float f) {
  unsigned int x = __float_as_uint(f);
  x += 0x7fffu + ((x >> 16) & 1u);  // RNE
  return (unsigned short)(x >> 16);
}
__device__ __forceinline__ float bf2f(unsigned short h) {
  return __uint_as_float((unsigned int)h << 16);
}
__device__ __forceinline__ void gl_lds16(const unsigned short* g,
                                         unsigned short* l) {
  __builtin_amdgcn_global_load_lds(
      (const __attribute__((address_space(1))) void*)g,
      (__attribute__((address_space(3))) void*)l, 16, 0, 0);
}
__device__ __forceinline__ void unpack8(bf16x8 v, float* f) {
  union { bf16x8 v8; unsigned int w[4]; } u;
  u.v8 = v;
#pragma unroll
  for (int i = 0; i < 4; ++i) {
    f[2 * i]     = __uint_as_float(u.w[i] << 16);
    f[2 * i + 1] = __uint_as_float(u.w[i] & 0xffff0000u);
  }
}
// bijective XCD-chunk swizzle (m204): contiguous wgid chunk per XCD
__device__ __forceinline__ int xcd_swz(int orig, int nwg) {
  const int q = nwg >> 3, r = nwg & 7;
  const int xcd = orig & 7, idx = orig >> 3;
  const int start = (xcd < r) ? xcd * (q + 1) : r * (q + 1) + (xcd - r) * q;
  return start + idx;
}

// ============================================================
// LayerNorm -> bf16 hi (+ optional lo). One block per row.
// ============================================================
template <bool LO>
__global__ __launch_bounds__(256) void ln_rows_bf(
    const float* __restrict__ X, const float* __restrict__ g,
    const float* __restrict__ bta, unsigned short* __restrict__ Yh,
    unsigned short* __restrict__ Yl) {
  const int r = blockIdx.x, tid = threadIdx.x;
  const float* row = X + (long)r * D_;
  float v[3];
  float s = 0.f, sq = 0.f;
#pragma unroll
  for (int t = 0; t < 3; ++t) {
    v[t] = row[tid + t * 256];
    s += v[t];
    sq = fmaf(v[t], v[t], sq);
  }
#pragma unroll
  for (int off = 32; off; off >>= 1) {
    s  += __shfl_xor(s, off);
    sq += __shfl_xor(sq, off);
  }
  __shared__ float rs[4], rq[4];
  if ((tid & 63) == 0) { rs[tid >> 6] = s; rq[tid >> 6] = sq; }
  __syncthreads();
  s  = rs[0] + rs[1] + rs[2] + rs[3];
  sq = rq[0] + rq[1] + rq[2] + rq[3];
  const float m   = s * (1.f / D_);
  const float var = sq * (1.f / D_) - m * m;
  const float inv = rsqrtf(var + 1e-5f);
#pragma unroll
  for (int t = 0; t < 3; ++t) {
    const int c = tid + t * 256;
    const float y = (v[t] - m) * inv * g[c] + bta[c];
    const unsigned short h = f2bf(y);
    Yh[(long)r * D_ + c] = h;
    if (LO) Yl[(long)r * D_ + c] = f2bf(y - bf2f(h));
  }
}

// ============================================================
// l2-normalize fp32 row -> bf16 hi/lo
// ============================================================
__global__ __launch_bounds__(256) void l2norm_hl(
    const float* __restrict__ X, unsigned short* __restrict__ Yh,
    unsigned short* __restrict__ Yl) {
  const int r = blockIdx.x, tid = threadIdx.x;
  const float* row = X + (long)r * D_;
  float v[3];
  float sq = 0.f;
#pragma unroll
  for (int t = 0; t < 3; ++t) {
    v[t] = row[tid + t * 256];
    sq = fmaf(v[t], v[t], sq);
  }
#pragma unroll
  for (int off = 32; off; off >>= 1) sq += __shfl_xor(sq, off);
  __shared__ float rq[4];
  if ((tid & 63) == 0) rq[tid >> 6] = sq;
  __syncthreads();
  sq = rq[0] + rq[1] + rq[2] + rq[3];
  const float sc = 1.f / fmaxf(sqrtf(sq), 1e-12f);
#pragma unroll
  for (int t = 0; t < 3; ++t) {
    const float y = v[t] * sc;
    const unsigned short h = f2bf(y);
    Yh[(long)r * D_ + tid + t * 256] = h;
    Yl[(long)r * D_ + tid + t * 256] = f2bf(y - bf2f(h));
  }
}

// ============================================================
// weight transpose fp32[K][N] -> bf16 [rowoff+N][K] hi (+lo)
// ============================================================
__global__ __launch_bounds__(256) void transpose_hl(
    const float* __restrict__ W, unsigned short* __restrict__ Th,
    unsigned short* __restrict__ Tl, int K, int N, int rowoff) {
  __shared__ float t[32][33];
  const int tx = threadIdx.x & 31, ty = threadIdx.x >> 5;
  const int n0 = blockIdx.x * 32, k0 = blockIdx.y * 32;
#pragma unroll
  for (int i = ty; i < 32; i += 8)
    t[i][tx] = W[(long)(k0 + i) * N + n0 + tx];
  __syncthreads();
#pragma unroll
  for (int i = ty; i < 32; i += 8) {
    const float w = t[tx][i];
    const unsigned short h = f2bf(w);
    const long o = (long)(rowoff + n0 + i) * K + k0 + tx;
    Th[o] = h;
    if (Tl) Tl[o] = f2bf(w - bf2f(h));
  }
}

// ============================================================
// bf16 MFMA GEMM: 128x128 tile, BK=64, swizzled LDS, XCD-chunked
// 1D grid = NB * MB (M-major per XCD chunk)
// ============================================================
enum { BEPI_QKV = 0, BEPI_ADD = 1, BEPI_GELU = 2 };

template <int EPI>
__global__ __launch_bounds__(256, 3) void gemm_bf16(
    const unsigned short* __restrict__ A, const unsigned short* __restrict__ Wt,
    const float* __restrict__ bias, const float* __restrict__ R,
    float* __restrict__ C, unsigned short* __restrict__ Cbf,
    int M, int N, int K,
    unsigned short* __restrict__ Qb, unsigned short* __restrict__ Kb,
    unsigned short* __restrict__ Vb) {
  constexpr int BK = 64;
  __shared__ __align__(16) unsigned short ldsA[128 * BK];  // 16 KB
  __shared__ __align__(16) unsigned short ldsB[128 * BK];  // 16 KB
  const int tid = threadIdx.x, wave = tid >> 6, lane = tid & 63;
  const int wr = wave >> 1, wc = wave & 1;
  const int l16 = lane & 15, l4 = lane >> 4;
  const int NB = N >> 7;
  const int wgid = xcd_swz(blockIdx.x, gridDim.x);
  const int bm = wgid / NB, bn = wgid - bm * NB;
  const int row0 = bm * 128;

  f32x4 acc[4][4];
#pragma unroll
  for (int i = 0; i < 4; ++i)
#pragma unroll
    for (int j = 0; j < 4; ++j) acc[i][j] = (f32x4){0.f, 0.f, 0.f, 0.f};

  // staging: chunk c -> LDS pos (row=c>>3, p=c&7); source slot s = p ^ (r&7)
  const unsigned short* ga[4];
  const unsigned short* gb[4];
#pragma unroll
  for (int t = 0; t < 4; ++t) {
    const int c = tid + (t << 8);
    const int r = c >> 3, p = c & 7, s = p ^ (r & 7);
    int ar = row0 + r; if (ar > M - 1) ar = M - 1;
    ga[t] = A + (long)ar * K + (s << 3);
    gb[t] = Wt + (long)(bn * 128 + r) * K + (s << 3);
  }

  for (int k0 = 0; k0 < K; k0 += BK) {
    __syncthreads();
#pragma unroll
    for (int t = 0; t < 4; ++t) {
      gl_lds16(ga[t] + k0, ldsA + ((tid + (t << 8)) << 3));
      gl_lds16(gb[t] + k0, ldsB + ((tid + (t << 8)) << 3));
    }
    __syncthreads();
#pragma unroll
    for (int sub = 0; sub < 2; ++sub) {
      bf16x8 af[4], bfr[4];
#pragma unroll
      for (int i = 0; i < 4; ++i) {
        const int row = wr * 64 + i * 16 + l16;
        const int pos = ((sub << 2) + l4) ^ (row & 7);
        af[i] = *(const bf16x8*)(ldsA + row * BK + (pos << 3));
      }
#pragma unroll
      for (int j = 0; j < 4; ++j) {
        const int row = wc * 64 + j * 16 + l16;
        const int pos = ((sub << 2) + l4) ^ (row & 7);
        bfr[j] = *(const bf16x8*)(ldsB + row * BK + (pos << 3));
      }
#pragma unroll
      for (int i = 0; i < 4; ++i)
#pragma unroll
        for (int j = 0; j < 4; ++j)
          acc[i][j] = __builtin_amdgcn_mfma_f32_16x16x32_bf16(af[i], bfr[j],
                                                              acc[i][j], 0, 0, 0);
    }
  }

#pragma unroll
  for (int j = 0; j < 4; ++j) {
    const int gcol = bn * 128 + wc * 64 + j * 16 + l16;
    const float bb = bias[gcol];
#pragma unroll
    for (int i = 0; i < 4; ++i) {
      const int grow0 = row0 + wr * 64 + i * 16 + l4 * 4;
#pragma unroll
      for (int r = 0; r < 4; ++r) {
        const int grow = grow0 + r;
        if (grow >= M) continue;
        float v = acc[i][j][r] + bb;
        if (EPI == BEPI_GELU) {
          v = 0.5f * v * (1.f + erff(v * 0.70710678118654752f));
          Cbf[(long)grow * N + gcol] = f2bf(v);
        } else if (EPI == BEPI_ADD) {
          C[(long)grow * N + gcol] = v + R[(long)grow * N + gcol];
        } else {  // BEPI_QKV: scatter bf16 to (B,H,S,HD)
          const int t   = gcol / (H_ * HD_);
          const int rem = gcol - t * (H_ * HD_);
          const int h   = rem >> 6;
          const int d   = rem & 63;
          const int b   = grow / S_;
          const int ss  = grow - b * S_;
          unsigned short* dst = (t == 0 ? Qb : (t == 1 ? Kb : Vb));
          dst[(((long)(b * H_ + h) * S_ + ss) << 6) + d] = f2bf(v);
        }
      }
    }
  }
}

// ============================================================
// routing projection: bf16x3 emulated-fp32, 4-tile staging
// per K-step: stage {Ahi,Alo,Whi,Wlo} once, 3 MFMA groups
// ============================================================
__global__ __launch_bounds__(256, 2) void gemm_rproj(
    const unsigned short* __restrict__ Ahi, const unsigned short* __restrict__ Alo,
    const unsigned short* __restrict__ Whi, const unsigned short* __restrict__ Wlo,
    const float* __restrict__ bq, const float* __restrict__ bk,
    float* __restrict__ qout, float* __restrict__ kout) {
  constexpr int BK = 32, K = D_, NB = 12;
  __shared__ __align__(16) unsigned short ldsAh[128 * BK];
  __shared__ __align__(16) unsigned short ldsAl[128 * BK];
  __shared__ __align__(16) unsigned short ldsBh[128 * BK];
  __shared__ __align__(16) unsigned short ldsBl[128 * BK];
  const int tid = threadIdx.x, wave = tid >> 6, lane = tid & 63;
  const int wr = wave >> 1, wc = wave & 1;
  const int l16 = lane & 15, l4 = lane >> 4;
  const int wgid = xcd_swz(blockIdx.x, gridDim.x);
  const int bm = wgid / NB, bn = wgid - bm * NB;
  const int row0 = bm * 128;

  f32x4 acc[4][4];
#pragma unroll
  for (int i = 0; i < 4; ++i)
#pragma unroll
    for (int j = 0; j < 4; ++j) acc[i][j] = (f32x4){0.f, 0.f, 0.f, 0.f};

  long aoff[2], boff[2];
#pragma unroll
  for (int t = 0; t < 2; ++t) {
    const int c = tid + (t << 8);
    const int r = c >> 2, p = c & 3, s = p ^ (r & 3);
    const int rg = row0 + r;
    aoff[t] = (long)(rg + rg / P_ + 1) * K + (s << 3);
    boff[t] = (long)(bn * 128 + r) * K + (s << 3);
  }

  for (int k0 = 0; k0 < K; k0 += BK) {
    __syncthreads();
#pragma unroll
    for (int t = 0; t < 2; ++t) {
      const int lo = (tid + (t << 8)) << 3;
      gl_lds16(Ahi + aoff[t] + k0, ldsAh + lo);
      gl_lds16(Alo + aoff[t] + k0, ldsAl + lo);
      gl_lds16(Whi + boff[t] + k0, ldsBh + lo);
      gl_lds16(Wlo + boff[t] + k0, ldsBl + lo);
    }
    __syncthreads();
    bf16x8 ah[4], al[4], bh[4], bl[4];
#pragma unroll
    for (int i = 0; i < 4; ++i) {
      const int row = wr * 64 + i * 16 + l16;
      const int off = row * BK + ((l4 ^ (row & 3)) << 3);
      ah[i] = *(const bf16x8*)(ldsAh + off);
      al[i] = *(const bf16x8*)(ldsAl + off);
    }
#pragma unroll
    for (int j = 0; j < 4; ++j) {
      const int row = wc * 64 + j * 16 + l16;
      const int off = row * BK + ((l4 ^ (row & 3)) << 3);
      bh[j] = *(const bf16x8*)(ldsBh + off);
      bl[j] = *(const bf16x8*)(ldsBl + off);
    }
#pragma unroll
    for (int i = 0; i < 4; ++i)
#pragma unroll
      for (int j = 0; j < 4; ++j) {
        acc[i][j] = __builtin_amdgcn_mfma_f32_16x16x32_bf16(ah[i], bh[j], acc[i][j], 0, 0, 0);
        acc[i][j] = __builtin_amdgcn_mfma_f32_16x16x32_bf16(ah[i], bl[j], acc[i][j], 0, 0, 0);
        acc[i][j] = __builtin_amdgcn_mfma_f32_16x16x32_bf16(al[i], bh[j], acc[i][j], 0, 0, 0);
      }
  }

#pragma unroll
  for (int j = 0; j < 4; ++j) {
    const int gcol = bn * 128 + wc * 64 + j * 16 + l16;
    const float bb = (gcol < D_) ? bq[gcol] : bk[gcol - D_];
#pragma unroll
    for (int i = 0; i < 4; ++i) {
      const int grow0 = row0 + wr * 64 + i * 16 + l4 * 4;
#pragma unroll
      for (int r = 0; r < 4; ++r) {
        const int grow = grow0 + r;
        const float v = acc[i][j][r] + bb;
        if (gcol < D_) qout[(long)grow * D_ + gcol] = v;
        else           kout[(long)grow * D_ + gcol - D_] = v;
      }
    }
  }
}

// ============================================================
// routing scores: batched bf16x3 NT, 4-tile staging
// ============================================================
__global__ __launch_bounds__(256, 2) void gemm_scores(
    const unsigned short* __restrict__ Qh, const unsigned short* __restrict__ Ql,
    const unsigned short* __restrict__ Kh, const unsigned short* __restrict__ Kl,
    const float* __restrict__ pos, float* __restrict__ sc) {
  constexpr int BK = 32, K = D_;
  __shared__ __align__(16) unsigned short ldsAh[128 * BK];
  __shared__ __align__(16) unsigned short ldsAl[128 * BK];
  __shared__ __align__(16) unsigned short ldsBh[128 * BK];
  __shared__ __align__(16) unsigned short ldsBl[128 * BK];
  const int tid = threadIdx.x, wave = tid >> 6, lane = tid & 63;
  const int wr = wave >> 1, wc = wave & 1;
  const int l16 = lane & 15, l4 = lane >> 4;
  const int bn = blockIdx.x, bm = blockIdx.y, b = blockIdx.z;
  const long base = (long)b * P_ * K;
  const int row0 = bm * 128;

  f32x4 acc[4][4];
#pragma unroll
  for (int i = 0; i < 4; ++i)
#pragma unroll
    for (int j = 0; j < 4; ++j) acc[i][j] = (f32x4){0.f, 0.f, 0.f, 0.f};

  long aoff[2], boff[2];
#pragma unroll
  for (int t = 0; t < 2; ++t) {
    const int c = tid + (t << 8);
    const int r = c >> 2, p = c & 3, s = p ^ (r & 3);
    int ar = row0 + r;      if (ar > P_ - 1) ar = P_ - 1;
    int br = bn * 128 + r;  if (br > P_ - 1) br = P_ - 1;
    aoff[t] = base + (long)ar * K + (s << 3);
    boff[t] = base + (long)br * K + (s << 3);
  }

  for (int k0 = 0; k0 < K; k0 += BK) {
    __syncthreads();
#pragma unroll
    for (int t = 0; t < 2; ++t) {
      const int lo = (tid + (t << 8)) << 3;
      gl_lds16(Qh + aoff[t] + k0, ldsAh + lo);
      gl_lds16(Ql + aoff[t] + k0, ldsAl + lo);
      gl_lds16(Kh + boff[t] + k0, ldsBh + lo);
      gl_lds16(Kl + boff[t] + k0, ldsBl + lo);
    }
    __syncthreads();
    bf16x8 ah[4], al[4], bh[4], bl[4];
#pragma unroll
    for (int i = 0; i < 4; ++i) {
      const int row = wr * 64 + i * 16 + l16;
      const int off = row * BK + ((l4 ^ (row & 3)) << 3);
      ah[i] = *(const bf16x8*)(ldsAh + off);
      al[i] = *(const bf16x8*)(ldsAl + off);
    }
#pragma unroll
    for (int j = 0; j < 4; ++j) {
      const int row = wc * 64 + j * 16 + l16;
      const int off = row * BK + ((l4 ^ (row & 3)) << 3);
      bh[j] = *(const bf16x8*)(ldsBh + off);
      bl[j] = *(const bf16x8*)(ldsBl + off);
    }
#pragma unroll
    for (int i = 0; i < 4; ++i)
#pragma unroll
      for (int j = 0; j < 4; ++j) {
        acc[i][j] = __builtin_amdgcn_mfma_f32_16x16x32_bf16(ah[i], bh[j], acc[i][j], 0, 0, 0);
        acc[i][j] = __builtin_amdgcn_mfma_f32_16x16x32_bf16(ah[i], bl[j], acc[i][j], 0, 0, 0);
        acc[i][j] = __builtin_amdgcn_mfma_f32_16x16x32_bf16(al[i], bh[j], acc[i][j], 0, 0, 0);
      }
  }

#pragma unroll
  for (int j = 0; j < 4; ++j) {
    const int gj = bn * 128 + wc * 64 + j * 16 + l16;
    if (gj >= P_) continue;
#pragma unroll
    for (int i = 0; i < 4; ++i) {
      const int grow0 = row0 + wr * 64 + i * 16 + l4 * 4;
#pragma unroll
      for (int r = 0; r < 4; ++r) {
        const int gi = grow0 + r;
        if (gi >= P_) continue;
        const float s = (gi == gj) ? -1e9f : acc[i][j][r] + pos[(long)gi * P_ + gj];
        sc[((long)b * P_ + gi) * P_ + gj] = s * INV_TEMP;
      }
    }
  }
}

// ============================================================
// top-32 + log-softmax weights. One wave per row.
// ============================================================
__global__ __launch_bounds__(64) void topk_route(
    const float* __restrict__ sc, int* __restrict__ routes,
    float* __restrict__ logw) {
  const int row = blockIdx.x, lane = threadIdx.x;
  const float* srow = sc + (long)row * P_;
  float v[9];
#pragma unroll
  for (int t = 0; t < 9; ++t) v[t] = srow[lane + (t << 6)];
  float selv = 0.f;
  int   selj = 0;
  for (int it = 0; it < KW_; ++it) {
    float bv = -3.0e38f;
    int   bj = 0x7fffffff;
#pragma unroll
    for (int t = 0; t < 9; ++t) {
      if (v[t] > bv) { bv = v[t]; bj = lane + (t << 6); }
    }
#pragma unroll
    for (int off = 32; off; off >>= 1) {
      const float ov = __shfl_xor(bv, off);
      const int   oj = __shfl_xor(bj, off);
      if (ov > bv || (ov == bv && oj < bj)) { bv = ov; bj = oj; }
    }
    if (lane == it) { selv = bv; selj = bj; }
    if ((bj & 63) == lane) v[bj >> 6] = -3.0e38f;
  }
  const float x = (lane < KW_) ? selv : -3.0e38f;
  float m = x;
#pragma unroll
  for (int off = 16; off; off >>= 1) m = fmaxf(m, __shfl_xor(m, off));
  const float e = expf(x - m);
  float s = e;
#pragma unroll
  for (int off = 16; off; off >>= 1) s += __shfl_xor(s, off);
  const float lw = fmaxf(x - m - logf(s), -10.0f);
  if (lane < KW_) {
    routes[(long)row * KW_ + lane] = selj;
    logw[(long)row * KW_ + lane]   = lw;
  }
}

// ============================================================
// patch attention v2 (unchanged from round 5)
// ============================================================
__global__ __launch_bounds__(1024, 1) void patch_attn2(
    const unsigned short* __restrict__ Qb, const unsigned short* __restrict__ Kb,
    const unsigned short* __restrict__ Vb, const int* __restrict__ routes,
    const float* __restrict__ logw, unsigned short* __restrict__ attn) {
  __shared__ __align__(16) unsigned short ldsK[P_ * HD_];
  __shared__ __align__(16) unsigned short ldsV[P_ * HD_];
  const int tid = threadIdx.x;
  const int b = blockIdx.x & 7;
  const int rest = blockIdx.x >> 3;
  const int phalf = rest & 1;
  const int h = rest >> 1;
  const long hb = ((long)(b * H_ + h) * S_) << 6;

  const unsigned short* kg = Kb + hb + HD_;
  const unsigned short* vg = Vb + hb + HD_;
#pragma unroll
  for (int c = tid; c < P_ * 8; c += 1024) {
    const int r = c >> 3, i = c & 7;
    const int lo = r * 64 + ((i * 8) ^ ((r & 7) << 3));
    *(bf16x8*)(ldsK + lo) = *(const bf16x8*)(kg + c * 8);
    *(bf16x8*)(ldsV + lo) = *(const bf16x8*)(vg + c * 8);
  }
  __syncthreads();

  const int wave = tid >> 6, lane = tid & 63;
  const int g = lane >> 3, ch = lane & 7;
  const int p0 = phalf * 288;

  for (int p = p0 + wave; p < p0 + 288; p += 16) {
    const int s = p + 1;
    const long bp32 = ((long)(b * P_ + p)) << 5;
    float qf[8];
    unpack8(*(const bf16x8*)(Qb + hb + ((long)s << 6) + ch * 8), qf);
    int   rk[4];
    float sc4[4];
    float m = -3.0e38f;
#pragma unroll
    for (int it = 0; it < 4; ++it) {
      const int key = it * 8 + g;
      rk[it] = routes[bp32 + key];
      float kf[8];
      unpack8(*(const bf16x8*)(ldsK + rk[it] * 64 +
                               ((ch * 8) ^ ((rk[it] & 7) << 3))), kf);
      float d0 = 0.f;
#pragma unroll
      for (int d = 0; d < 8; ++d) d0 = fmaf(qf[d], kf[d], d0);
      d0 += __shfl_xor(d0, 1);
      d0 += __shfl_xor(d0, 2);
      d0 += __shfl_xor(d0, 4);
      sc4[it] = fmaf(d0, SCALE_, logw[bp32 + key]);
      m = fmaxf(m, sc4[it]);
    }
    m = fmaxf(m, __shfl_xor(m, 8));
    m = fmaxf(m, __shfl_xor(m, 16));
    m = fmaxf(m, __shfl_xor(m, 32));
    float e4[4], lsum = 0.f;
#pragma unroll
    for (int it = 0; it < 4; ++it) {
      e4[it] = __expf(sc4[it] - m);
      lsum += e4[it];
    }
    lsum += __shfl_xor(lsum, 8);
    lsum += __shfl_xor(lsum, 16);
    lsum += __shfl_xor(lsum, 32);
    float facc[8];
#pragma unroll
    for (int d = 0; d < 8; ++d) facc[d] = 0.f;
#pragma unroll
    for (int it = 0; it < 4; ++it) {
      float vf[8];
      unpack8(*(const bf16x8*)(ldsV + rk[it] * 64 +
                               ((ch * 8) ^ ((rk[it] & 7) << 3))), vf);
#pragma unroll
      for (int d = 0; d < 8; ++d) facc[d] = fmaf(e4[it], vf[d], facc[d]);
    }
#pragma unroll
    for (int off = 8; off <= 32; off <<= 1)
#pragma unroll
      for (int d = 0; d < 8; ++d) facc[d] += __shfl_xor(facc[d], off);
    const float inv = 1.f / lsum;
    if (lane < 8) {
      union { bf16x8 v8; unsigned short u[8]; } o;
#pragma unroll
      for (int d = 0; d < 8; ++d) o.u[d] = f2bf(facc[d] * inv);
      *(bf16x8*)(attn + ((long)b * S_ + s) * D_ + h * HD_ + ch * 8) = o.v8;
    }
  }
}

// ============================================================
// cls-token attention (bf16 in/out)
// ============================================================
__global__ __launch_bounds__(256) void cls_attn(
    const unsigned short* __restrict__ Qb, const unsigned short* __restrict__ Kb,
    const unsigned short* __restrict__ Vb, unsigned short* __restrict__ attn) {
  const int bh = blockIdx.x;
  const int b = bh / H_, h = bh - b * H_;
  const int tid = threadIdx.x;
  __shared__ float qs[HD_];
  __shared__ float ssh[S_];
  __shared__ float redm[4], reds[4];
  __shared__ float osh[4][HD_];
  const unsigned short* Qrow  = Qb + (long)bh * S_ * HD_;
  const unsigned short* Kbase = Kb + (long)bh * S_ * HD_;
  const unsigned short* Vbase = Vb + (long)bh * S_ * HD_;
  if (tid < HD_) qs[tid] = bf2f(Qrow[tid]);
  __syncthreads();
  float lmax = -3.0e38f;
  for (int j = tid; j < S_; j += 256) {
    const unsigned short* kr = Kbase + (long)j * HD_;
    float dot = 0.f;
#pragma unroll
    for (int dd = 0; dd < HD_; dd += 8) {
      float kf[8];
      unpack8(*(const bf16x8*)(kr + dd), kf);
#pragma unroll
      for (int t = 0; t < 8; ++t) dot = fmaf(kf[t], qs[dd + t], dot);
    }
    dot *= SCALE_;
    ssh[j] = dot;
    lmax = fmaxf(lmax, dot);
  }
#pragma unroll
  for (int off = 32; off; off >>= 1) lmax = fmaxf(lmax, __shfl_xor(lmax, off));
  if ((tid & 63) == 0) redm[tid >> 6] = lmax;
  __syncthreads();
  const float m = fmaxf(fmaxf(redm[0], redm[1]), fmaxf(redm[2], redm[3]));
  float lsum = 0.f;
  for (int j = tid; j < S_; j += 256) {
    const float e = expf(ssh[j] - m);
    ssh[j] = e;
    lsum += e;
  }
#pragma unroll
  for (int off = 32; off; off >>= 1) lsum += __shfl_xor(lsum, off);
  if ((tid & 63) == 0) reds[tid >> 6] = lsum;
  __syncthreads();
  const float inv = 1.f / (reds[0] + reds[1] + reds[2] + reds[3]);
  const int d = tid & 63, qt = tid >> 6;
  float acc = 0.f;
  for (int j = qt; j < S_; j += 4)
    acc = fmaf(ssh[j], bf2f(Vbase[((long)j << 6) + d]), acc);
  osh[qt][d] = acc;
  __syncthreads();
  if (tid < HD_) {
    const float o = (osh[0][tid] + osh[1][tid] + osh[2][tid] + osh[3][tid]) * inv;
    attn[(long)b * S_ * D_ + h * HD_ + tid] = f2bf(o);
  }
}

// ============================================================
// host-side launch
// ============================================================
extern "C" void kernel_launch(void* const* d_in, const int* in_sizes, int n_in,
                              void* d_out, int out_size, void* d_ws,
                              size_t ws_size, hipStream_t stream) {
  const float* x     = (const float*)d_in[0];
  const float* g1    = (const float*)d_in[1];
  const float* b1    = (const float*)d_in[2];
  const float* wq    = (const float*)d_in[3];
  const float* bq    = (const float*)d_in[4];
  const float* wk    = (const float*)d_in[5];
  const float* bk    = (const float*)d_in[6];
  const float* pos   = (const float*)d_in[7];
  const float* wqkv  = (const float*)d_in[8];
  const float* bqkv  = (const float*)d_in[9];
  const float* wproj = (const float*)d_in[10];
  const float* bproj = (const float*)d_in[11];
  const float* g2    = (const float*)d_in[12];
  const float* b2    = (const float*)d_in[13];
  const float* wm1   = (const float*)d_in[14];
  const float* bm1   = (const float*)d_in[15];
  const float* wm2   = (const float*)d_in[16];
  const float* bm2   = (const float*)d_in[17];
  float* out = (float*)d_out;

  constexpr long NSD = (long)MS * D_;       // 3,545,088 (== B*H*S*HD)
  constexpr long MPD = (long)MP * D_;       // 3,538,944
  constexpr long SCL = (long)B_ * P_ * P_;  // 2,654,208

  unsigned short* xn_hi = (unsigned short*)d_ws;
  unsigned short* xn_lo = xn_hi + NSD;
  float* x1 = (float*)(xn_lo + NSD);
  unsigned short* Qb = (unsigned short*)(x1 + NSD);
  unsigned short* Kb = Qb + NSD;
  unsigned short* Vb = Kb + NSD;
  int*   routes = (int*)(Vb + NSD);
  float* logw   = (float*)(routes + (long)MP * KW_);
  float* R1   = logw + (long)MP * KW_;
  float* qbuf = R1;
  float* kbuf = qbuf + MPD;
  unsigned short* h_bf = (unsigned short*)R1;        // 4616*3072 shorts
  constexpr long R1LEN = ((long)MS * 3072 + 1) / 2;  // floats
  float* scb = R1 + R1LEN;
  unsigned short* qh = (unsigned short*)(scb + SCL);
  unsigned short* ql = qh + MPD;
  unsigned short* kh = ql + MPD;
  unsigned short* kl = kh + MPD;
  unsigned short* x1n_bf  = qh;        // NSD shorts, live after scores dead
  unsigned short* attn_bf = qh + NSD;  // NSD shorts
  unsigned short* wqk_hi  = kl + MPD;                   // [1536][768]
  unsigned short* wqk_lo  = wqk_hi + (long)1536 * 768;
  unsigned short* wqkv_t  = wqk_lo + (long)1536 * 768;  // [2304][768]
  unsigned short* wproj_t = wqkv_t + (long)2304 * 768;  // [768][768]
  unsigned short* wm1_t   = wproj_t + (long)768 * 768;  // [3072][768]
  unsigned short* wm2_t   = wm1_t + (long)3072 * 768;   // [768][3072]

  // weight prep
  transpose_hl<<<dim3(24, 24), 256, 0, stream>>>(wq, wqk_hi, wqk_lo, 768, 768, 0);
  transpose_hl<<<dim3(24, 24), 256, 0, stream>>>(wk, wqk_hi, wqk_lo, 768, 768, 768);
  transpose_hl<<<dim3(72, 24), 256, 0, stream>>>(wqkv, wqkv_t, nullptr, 768, 2304, 0);
  transpose_hl<<<dim3(24, 24), 256, 0, stream>>>(wproj, wproj_t, nullptr, 768, 768, 0);
  transpose_hl<<<dim3(96, 24), 256, 0, stream>>>(wm1, wm1_t, nullptr, 768, 3072, 0);
  transpose_hl<<<dim3(24, 96), 256, 0, stream>>>(wm2, wm2_t, nullptr, 3072, 768, 0);

  // 1. LN1 -> bf16 hi/lo
  ln_rows_bf<true><<<MS, 256, 0, stream>>>(x, g1, b1, xn_hi, xn_lo);
  // 2. routing projections (bf16x3), q|k fused, 4-tile staging
  gemm_rproj<<<12 * 36, 256, 0, stream>>>(xn_hi, xn_lo, wqk_hi, wqk_lo, bq, bk,
                                          qbuf, kbuf);
  // 3. l2norm -> hi/lo
  l2norm_hl<<<MP, 256, 0, stream>>>(qbuf, qh, ql);
  l2norm_hl<<<MP, 256, 0, stream>>>(kbuf, kh, kl);
  // 4. routing scores (bf16x3, batched, fused pos/diag/x10)
  gemm_scores<<<dim3(5, 5, B_), 256, 0, stream>>>(qh, ql, kh, kl, pos, scb);
  // 5. top-32 + log-softmax
  topk_route<<<MP, 64, 0, stream>>>(scb, routes, logw);
  // 6. fused QKV projection (bf16 MFMA) -> (B,H,S,HD) bf16
  gemm_bf16<BEPI_QKV><<<18 * 37, 256, 0, stream>>>(
      xn_hi, wqkv_t, bqkv, nullptr, nullptr, nullptr, MS, 2304, D_, Qb, Kb, Vb);
  // 7. attention (bf16 in, fp32 compute, bf16 out)
  cls_attn<<<B_ * H_, 256, 0, stream>>>(Qb, Kb, Vb, attn_bf);
  patch_attn2<<<192, 1024, 0, stream>>>(Qb, Kb, Vb, routes, logw, attn_bf);
  // 8. output projection + residual
  gemm_bf16<BEPI_ADD><<<6 * 37, 256, 0, stream>>>(
      attn_bf, wproj_t, bproj, x, x1, nullptr, MS, D_, D_, nullptr, nullptr,
      nullptr);
  // 9. LN2 + MLP
  ln_rows_bf<false><<<MS, 256, 0, stream>>>(x1, g2, b2, x1n_bf, nullptr);
  gemm_bf16<BEPI_GELU><<<24 * 37, 256, 0, stream>>>(
      x1n_bf, wm1_t, bm1, nullptr, nullptr, h_bf, MS, 3072, D_, nullptr,
      nullptr, nullptr);
  gemm_bf16<BEPI_ADD><<<6 * 37, 256, 0, stream>>>(
      h_bf, wm2_t, bm2, x1, out, nullptr, MS, D_, 3072, nullptr, nullptr,
      nullptr);
}